// Round 1
// 1113.967 us; speedup vs baseline: 1.2192x; 1.2192x over previous
//
#include <hip/hip_runtime.h>

typedef unsigned short u16;
typedef unsigned int u32;

typedef __bf16 bf16x8 __attribute__((ext_vector_type(8)));
typedef float f32x4 __attribute__((ext_vector_type(4)));

#define DIM 768
#define HID 3072
#define NTOK 196
#define BT 128
#define NTOKENS (BT * NTOK)   // 25088
#define MJ 3136               // FRAMES * NTOK
#define HEADS 12

// workspace layout sizes (bytes)
#define SZ_WB   ((size_t)(2304*768 + 768*768 + 3072*768 + 768*3072) * 2)  // bf16 weights
#define SZ_XN   ((size_t)NTOKENS * DIM * 2)
#define SZ_QKV  ((size_t)NTOKENS * 2304 * 2)
#define SZ_X2   ((size_t)NTOKENS * DIM * 4)
#define SZ_HDN  ((size_t)NTOKENS * HID * 2)
#define SZ_KV   ((size_t)96 * 4096 * 4)
#define SZ_KS   ((size_t)96 * 64 * 4)
#define WS_NEED (SZ_WB + SZ_XN + SZ_QKV + SZ_X2 + SZ_HDN + SZ_KV + SZ_KS)

static void* g_buf = nullptr;

__device__ __forceinline__ float b2f(u16 u) {
  union { u32 i; float f; } x; x.i = ((u32)u) << 16; return x.f;
}
__device__ __forceinline__ u16 f2b(float f) {
  u32 x = __float_as_uint(f);
  return (u16)((x + 0x7fffu + ((x >> 16) & 1u)) >> 16);
}

// async 16B global->LDS (gfx950). LDS dest = wave-uniform base + lane*16.
__device__ __forceinline__ void gload_lds16(const u16* g, u16* l) {
  __builtin_amdgcn_global_load_lds(
      (const __attribute__((address_space(1))) u32*)g,
      (__attribute__((address_space(3))) u32*)l, 16, 0, 0);
}

// ---------------- f32 -> bf16 conversion (weights) ----------------
__global__ __launch_bounds__(256) void cvt_f32_bf16(const float* __restrict__ in,
    u16* __restrict__ out, int n4)
{
  int i = blockIdx.x * 256 + threadIdx.x;
  if (i < n4) {
    float4 f = ((const float4*)in)[i];
    ushort4 r;
    r.x = f2b(f.x); r.y = f2b(f.y); r.z = f2b(f.z); r.w = f2b(f.w);
    ((ushort4*)out)[i] = r;
  }
}

// ---------------- zero-fill for KV/KS accumulators ----------------
__global__ __launch_bounds__(256) void zero_f32(float* __restrict__ p, int n) {
  int i = blockIdx.x * 256 + threadIdx.x;
  if (i < n) p[i] = 0.0f;
}

// ---------------- LayerNorm: one wave per token, fp32 in, bf16 out ---------
__global__ __launch_bounds__(256) void ln_kernel(const float* __restrict__ xin,
    const float* __restrict__ w, const float* __restrict__ b, u16* __restrict__ out)
{
  const int token = blockIdx.x * 4 + (threadIdx.x >> 6);
  const int lane = threadIdx.x & 63;
  float v[12];
  const float* x = xin + (size_t)token * DIM;
#pragma unroll
  for (int c = 0; c < 3; ++c) {
    float4 f = *(const float4*)(x + c * 256 + lane * 4);
    v[c*4+0] = f.x; v[c*4+1] = f.y; v[c*4+2] = f.z; v[c*4+3] = f.w;
  }
  float s = 0.f, sq = 0.f;
#pragma unroll
  for (int i = 0; i < 12; ++i) { s += v[i]; sq += v[i] * v[i]; }
#pragma unroll
  for (int off = 32; off > 0; off >>= 1) {
    s += __shfl_xor(s, off, 64);
    sq += __shfl_xor(sq, off, 64);
  }
  const float mean = s * (1.0f / 768.0f);
  const float var = sq * (1.0f / 768.0f) - mean * mean;
  const float rstd = rsqrtf(var + 1e-5f);
  u16* o = out + (size_t)token * DIM;
#pragma unroll
  for (int c = 0; c < 3; ++c) {
    float4 wv = *(const float4*)(w + c * 256 + lane * 4);
    float4 bv = *(const float4*)(b + c * 256 + lane * 4);
    ushort4 r;
    r.x = f2b((v[c*4+0] - mean) * rstd * wv.x + bv.x);
    r.y = f2b((v[c*4+1] - mean) * rstd * wv.y + bv.y);
    r.z = f2b((v[c*4+2] - mean) * rstd * wv.z + bv.z);
    r.w = f2b((v[c*4+3] - mean) * rstd * wv.w + bv.w);
    *(ushort4*)(o + c * 256 + lane * 4) = r;
  }
}

// ================= 256x256 8-phase MFMA GEMM (T2+T3+T4+T5) =================
// C[M,N] = A[M,K] * W[N,K]^T, fused epilogues (MODE as before).
// BM=BN=256, BK=64, 8 waves (2Mx4N), per-wave 128x64 output = acc[8][4].
// LDS 128 KiB dynamic: A[2][256][64] + B[2][256][64] bf16, XOR-swizzled:
//   physical byte = row*128 + (colbyte ^ ((row&7)<<4))   (involution)
// Staged via global_load_lds (linear LDS dest) with pre-swizzled global src.
// Per K-tile: 4 phases {ds_read | stage 1 half-tile | barrier | lgkm0 |
// setprio(1) 16xMFMA setprio(0) | barrier}; counted vmcnt(2) once per tile
// (never 0 in steady state) -- tile t+1's halves staged at P3(t-1)..P2(t).
// MODE 0: QKV  (relu+0.125 on cols<1536; bf16 out)
// MODE 1: PROJ (fp32 bias + fp32 residual; fp32 out)
// MODE 2: FC1  (fp32 bias; bf16 out)
// MODE 3: FC2  (fp32 bias + fp32 residual; fp32 out)
template<int MODE, int NXT, int NN, int KK>
__global__ __launch_bounds__(512, 2) void gemm8(
    const u16* __restrict__ A, const u16* __restrict__ W,
    const float* __restrict__ bias, const float* __restrict__ res,
    void* __restrict__ out)
{
  extern __shared__ char smem[];
  u16* As = (u16*)smem;                 // 2 x 16384 u16 (64 KB)
  u16* Bs = (u16*)(smem + 65536);       // 2 x 16384 u16 (64 KB)

  const int t = threadIdx.x;
  const int l = t & 63;
  const int w = t >> 6;           // wave 0..7
  const int wm = w >> 2;          // m-half 0..1
  const int wn = w & 3;           // n-quarter 0..3

  // bijective XCD swizzle (m204): consecutive wgid per XCD -> same m-panel
  constexpr int TOTAL = 98 * NXT;
  constexpr int Q8 = TOTAL >> 3;
  constexpr int R8 = TOTAL & 7;
  const int orig = blockIdx.x;
  const int xcd = orig & 7;
  const int idx = orig >> 3;
  const int wg = (xcd < R8) ? (xcd * (Q8 + 1) + idx)
                            : (R8 * (Q8 + 1) + (xcd - R8) * Q8 + idx);
  const int m0 = (wg / NXT) * 256;
  const int n0 = (wg % NXT) * 256;

  // ---- staging: linear LDS dest byte (in half) = (2w+i)*1024 + l*16
  //      -> row = (2w+i)*8 + (l>>3), colbyte = (l&7)*16
  //      pre-swizzled source col element = ((l&7)^(l>>3))*8
  const int srow = w * 16 + (l >> 3);
  const int scol = ((l & 7) ^ (l >> 3)) * 8;
  const u16* gA = A + (size_t)(m0 + srow) * KK + scol;
  const u16* gB = W + (size_t)(n0 + srow) * KK + scol;
  u16* lA = As + w * 1024;   // u16 elems; +bb*16384 +h*8192 ; +512 for i=1
  u16* lB = Bs + w * 1024;

#define STAGE_A(bb, h, kt) do { \
    const u16* g_ = gA + (size_t)(h) * 128 * KK + (size_t)(kt) * 64; \
    u16* l_ = lA + (bb) * 16384 + (h) * 8192; \
    gload_lds16(g_, l_); \
    gload_lds16(g_ + (size_t)8 * KK, l_ + 512); } while (0)
#define STAGE_B(bb, h, kt) do { \
    const u16* g_ = gB + (size_t)(h) * 128 * KK + (size_t)(kt) * 64; \
    u16* l_ = lB + (bb) * 16384 + (h) * 8192; \
    gload_lds16(g_, l_); \
    gload_lds16(g_ + (size_t)8 * KK, l_ + 512); } while (0)

  // ---- compute-side swizzled ds_read byte offsets ----
  const int lm = l & 15;
  const int qq = l >> 4;
  const int acol = (qq << 4) ^ ((l & 7) << 4);          // kk=0; kk=1 -> ^64
  const int abase = (wm * 128 + lm) * 128 + acol;       // +mq*8192 +mi*2048
  const int bbase = (wn * 64 + lm) * 128 + acol;        // +ni*2048

  f32x4 acc[8][4];
#pragma unroll
  for (int mi = 0; mi < 8; ++mi)
#pragma unroll
    for (int ni = 0; ni < 4; ++ni) acc[mi][ni] = (f32x4){0.f, 0.f, 0.f, 0.f};

  constexpr int NT = KK / 64;

  // prologue: tile0 fully + hA0(1); vmcnt(2) keeps hA0(1) in flight
  STAGE_A(0, 0, 0); STAGE_A(0, 1, 0); STAGE_B(0, 0, 0); STAGE_B(0, 1, 0);
  STAGE_A(1, 0, 1);
  asm volatile("s_waitcnt vmcnt(2)" ::: "memory");
  __builtin_amdgcn_s_barrier();

  for (int ti = 0; ti < NT; ++ti) {
    const int cb = ti & 1, nb = cb ^ 1;
    const char* Ac = (const char*)As + cb * 32768;
    const char* Bc = (const char*)Bs + cb * 32768;
    bf16x8 am[4][2], b01[2][2], b23[2][2];

    // ---- P0: read A mq0 (8) + B n0,n1 (4); stage hA1(t+1) ----
#pragma unroll
    for (int mi = 0; mi < 4; ++mi) {
      const int off = abase + mi * 2048;
      am[mi][0] = *(const bf16x8*)(Ac + off);
      am[mi][1] = *(const bf16x8*)(Ac + (off ^ 64));
    }
#pragma unroll
    for (int ni = 0; ni < 2; ++ni) {
      const int off = bbase + ni * 2048;
      b01[ni][0] = *(const bf16x8*)(Bc + off);
      b01[ni][1] = *(const bf16x8*)(Bc + (off ^ 64));
    }
    if (ti + 1 < NT) STAGE_A(nb, 1, ti + 1);
    asm volatile("" ::: "memory");
    __builtin_amdgcn_s_barrier();
    asm volatile("s_waitcnt lgkmcnt(0)" ::: "memory");
    __builtin_amdgcn_s_setprio(1);
#pragma unroll
    for (int mi = 0; mi < 4; ++mi)
#pragma unroll
      for (int ni = 0; ni < 2; ++ni) {
        acc[mi][ni] = __builtin_amdgcn_mfma_f32_16x16x32_bf16(am[mi][0], b01[ni][0], acc[mi][ni], 0, 0, 0);
        acc[mi][ni] = __builtin_amdgcn_mfma_f32_16x16x32_bf16(am[mi][1], b01[ni][1], acc[mi][ni], 0, 0, 0);
      }
    __builtin_amdgcn_s_setprio(0);
    asm volatile("" ::: "memory");
    __builtin_amdgcn_s_barrier();

    // ---- P1: read B n2,n3 (4); stage hB0(t+1) ----
#pragma unroll
    for (int ni = 0; ni < 2; ++ni) {
      const int off = bbase + (ni + 2) * 2048;
      b23[ni][0] = *(const bf16x8*)(Bc + off);
      b23[ni][1] = *(const bf16x8*)(Bc + (off ^ 64));
    }
    if (ti + 1 < NT) STAGE_B(nb, 0, ti + 1);
    asm volatile("" ::: "memory");
    __builtin_amdgcn_s_barrier();
    asm volatile("s_waitcnt lgkmcnt(0)" ::: "memory");
    __builtin_amdgcn_s_setprio(1);
#pragma unroll
    for (int mi = 0; mi < 4; ++mi)
#pragma unroll
      for (int ni = 0; ni < 2; ++ni) {
        acc[mi][ni + 2] = __builtin_amdgcn_mfma_f32_16x16x32_bf16(am[mi][0], b23[ni][0], acc[mi][ni + 2], 0, 0, 0);
        acc[mi][ni + 2] = __builtin_amdgcn_mfma_f32_16x16x32_bf16(am[mi][1], b23[ni][1], acc[mi][ni + 2], 0, 0, 0);
      }
    __builtin_amdgcn_s_setprio(0);
    asm volatile("" ::: "memory");
    __builtin_amdgcn_s_barrier();

    // ---- P2: read A mq1 (8); stage hB1(t+1) ----
#pragma unroll
    for (int mi = 0; mi < 4; ++mi) {
      const int off = abase + 8192 + mi * 2048;
      am[mi][0] = *(const bf16x8*)(Ac + off);
      am[mi][1] = *(const bf16x8*)(Ac + (off ^ 64));
    }
    if (ti + 1 < NT) STAGE_B(nb, 1, ti + 1);
    asm volatile("" ::: "memory");
    __builtin_amdgcn_s_barrier();
    asm volatile("s_waitcnt lgkmcnt(0)" ::: "memory");
    __builtin_amdgcn_s_setprio(1);
#pragma unroll
    for (int mi = 0; mi < 4; ++mi)
#pragma unroll
      for (int ni = 0; ni < 2; ++ni) {
        acc[mi + 4][ni + 2] = __builtin_amdgcn_mfma_f32_16x16x32_bf16(am[mi][0], b23[ni][0], acc[mi + 4][ni + 2], 0, 0, 0);
        acc[mi + 4][ni + 2] = __builtin_amdgcn_mfma_f32_16x16x32_bf16(am[mi][1], b23[ni][1], acc[mi + 4][ni + 2], 0, 0, 0);
      }
    __builtin_amdgcn_s_setprio(0);
    asm volatile("" ::: "memory");
    __builtin_amdgcn_s_barrier();

    // ---- P3: stage hA0(t+2) into cb (hA0(t) fully consumed at P2);
    //      counted vmcnt: tile t+1 resident, newest half-tile in flight ----
    if (ti + 2 < NT) {
      STAGE_A(cb, 0, ti + 2);
      asm volatile("s_waitcnt vmcnt(2)" ::: "memory");
    } else {
      asm volatile("s_waitcnt vmcnt(0)" ::: "memory");
    }
    __builtin_amdgcn_s_barrier();
    __builtin_amdgcn_s_setprio(1);
#pragma unroll
    for (int mi = 0; mi < 4; ++mi)
#pragma unroll
      for (int ni = 0; ni < 2; ++ni) {
        acc[mi + 4][ni] = __builtin_amdgcn_mfma_f32_16x16x32_bf16(am[mi][0], b01[ni][0], acc[mi + 4][ni], 0, 0, 0);
        acc[mi + 4][ni] = __builtin_amdgcn_mfma_f32_16x16x32_bf16(am[mi][1], b01[ni][1], acc[mi + 4][ni], 0, 0, 0);
      }
    __builtin_amdgcn_s_setprio(0);
    asm volatile("" ::: "memory");
    __builtin_amdgcn_s_barrier();
  }
#undef STAGE_A
#undef STAGE_B

  // ---- epilogue: C row = m0+wm*128+mi*16+qq*4+r, col = n0+wn*64+ni*16+lm
#pragma unroll
  for (int mi = 0; mi < 8; ++mi) {
    const int rbase = m0 + wm * 128 + mi * 16 + qq * 4;
#pragma unroll
    for (int ni = 0; ni < 4; ++ni) {
      const int col = n0 + wn * 64 + ni * 16 + lm;
      float bv = 0.f;
      if (MODE != 0) bv = bias[col];
#pragma unroll
      for (int r = 0; r < 4; ++r) {
        float v = acc[mi][ni][r];
        const size_t idxo = (size_t)(rbase + r) * NN + col;
        if (MODE == 0) {
          if (col < 1536) v = fmaxf(v, 0.0f) + 0.125f;
          ((u16*)out)[idxo] = f2b(v);
        } else if (MODE == 1) {
          ((float*)out)[idxo] = v + bv + res[idxo];
        } else if (MODE == 2) {
          ((u16*)out)[idxo] = f2b(v + bv);
        } else {
          ((float*)out)[idxo] = v + bv + res[idxo];
        }
      }
    }
  }
}

// ---------------- kv = sum_m k_ (outer) v ; ksum = sum_m k_  ----------------
__global__ __launch_bounds__(256) void kv_reduce(const u16* __restrict__ qkv,
    float* __restrict__ kv, float* __restrict__ ksum)
{
  const int bh = blockIdx.x;       // b*12+h
  const int s = blockIdx.y;        // 0..7
  const int b = bh / 12, h = bh % 12;
  __shared__ __align__(16) u16 ks[64 * 64];
  __shared__ __align__(16) u16 vs[64 * 64];
  const int t = threadIdx.x;
  const int e = t & 63;
  const int dg = (t >> 6) * 16;

  float acc[16];
#pragma unroll
  for (int j = 0; j < 16; ++j) acc[j] = 0.f;
  float ksacc = 0.f;

  for (int ch = s; ch < 49; ch += 8) {
    const size_t tokbase = (size_t)b * MJ + ch * 64;
    __syncthreads();
#pragma unroll
    for (int i = 0; i < 2; ++i) {
      int c = t + i * 256;
      int row = c >> 3, eo = (c & 7) * 8;
      const u16* base = qkv + (tokbase + row) * 2304 + h * 64 + eo;
      *(uint4*)&ks[row * 64 + eo] = *(const uint4*)(base + 768);
      *(uint4*)&vs[row * 64 + eo] = *(const uint4*)(base + 1536);
    }
    __syncthreads();
    for (int m = 0; m < 64; ++m) {
      float kf = b2f(ks[m * 64 + e]);
      ksacc += kf;
      bf16x8 v0 = *(const bf16x8*)&vs[m * 64 + dg];
      bf16x8 v1 = *(const bf16x8*)&vs[m * 64 + dg + 8];
#pragma unroll
      for (int j = 0; j < 8; ++j) {
        acc[j]     += kf * (float)v0[j];
        acc[j + 8] += kf * (float)v1[j];
      }
    }
  }
  float* dst = kv + (size_t)bh * 4096 + e * 64 + dg;
#pragma unroll
  for (int j = 0; j < 16; ++j) atomicAdd(&dst[j], acc[j]);
  if (dg == 0) atomicAdd(&ksum[bh * 64 + e], ksacc);
}

// ---------------- out = (q_ @ kv) * z ----------------
__global__ __launch_bounds__(256) void attn_out(const u16* __restrict__ qkv,
    const float* __restrict__ kv, const float* __restrict__ ksum,
    u16* __restrict__ outp)
{
  const int chunk = blockIdx.x;   // 0..48
  const int h = blockIdx.y;       // 0..11
  const int b = blockIdx.z;       // 0..7
  __shared__ float kvs[4096];
  __shared__ float kss[64];
  __shared__ float qs[4096];      // [wave][16 tok][64 e]
  const int t = threadIdx.x;
  const float* kvsrc = kv + (size_t)(b * 12 + h) * 4096;
  for (int i = t; i < 1024; i += 256)
    ((float4*)kvs)[i] = ((const float4*)kvsrc)[i];
  if (t < 64) kss[t] = ksum[(b * 12 + h) * 64 + t];
  __syncthreads();
  const int wv = t >> 6, lane = t & 63;
  float* qw = &qs[wv * 1024];
  const size_t tok0 = (size_t)b * MJ + chunk * 64 + wv * 16;
#pragma unroll
  for (int i = 0; i < 16; ++i) {
    float q = b2f(qkv[(tok0 + i) * 2304 + h * 64 + lane]);
    float pd = q * kss[lane];
#pragma unroll
    for (int off = 32; off > 0; off >>= 1) pd += __shfl_xor(pd, off, 64);
    qw[i * 64 + lane] = q * (1.0f / (pd + 1e-6f));
  }
  float o[16];
#pragma unroll
  for (int i = 0; i < 16; ++i) o[i] = 0.f;
  for (int e = 0; e < 64; ++e) {
    const float kvc = kvs[e * 64 + lane];
#pragma unroll
    for (int i = 0; i < 16; ++i) o[i] += qw[i * 64 + e] * kvc;
  }
#pragma unroll
  for (int i = 0; i < 16; ++i)
    outp[(tok0 + i) * 768 + h * 64 + lane] = f2b(o[i]);
}

// ---------------- depthwise 3x3 conv + exact GELU, in place --------------
__global__ __launch_bounds__(256) void dwconv_gelu(u16* __restrict__ hdn,
    const float* __restrict__ w, const float* __restrict__ bias)
{
  __shared__ u16 pl[196 * 64];
  const int cb = blockIdx.x;     // 0..47
  const int fr = blockIdx.y;     // 0..127
  const int t = threadIdx.x;
  const int c0 = cb * 64;
  u16* base = hdn + (size_t)fr * 196 * HID + c0;
  for (int i = 0; i < 49; ++i) {
    int idx = i * 256 + t;
    int p = idx >> 6, c = idx & 63;
    pl[idx] = base[(size_t)p * HID + c];
  }
  __syncthreads();
  const int c = t & 63;
  const int pg = t >> 6;
  float wr[9];
#pragma unroll
  for (int k = 0; k < 9; ++k) wr[k] = w[(c0 + c) * 9 + k];
  const float bv = bias[c0 + c];
  for (int j = 0; j < 49; ++j) {
    const int p = pg + j * 4;
    const int py = p / 14, px = p % 14;
    float a = bv;
#pragma unroll
    for (int ky = 0; ky < 3; ++ky) {
      int yy = py + ky - 1;
      if (yy < 0 || yy > 13) continue;
#pragma unroll
      for (int kx = 0; kx < 3; ++kx) {
        int xx = px + kx - 1;
        if (xx < 0 || xx > 13) continue;
        a += wr[ky * 3 + kx] * b2f(pl[(yy * 14 + xx) * 64 + c]);
      }
    }
    float g = 0.5f * a * (1.0f + erff(a * 0.70710678118654752f));
    base[(size_t)p * HID + c] = f2b(g);
  }
}

// ---- dynamic-LDS attribute (128 KiB > 64 KiB default) + fallback buffer ----
static void set_gemm_attrs() {
  (void)hipFuncSetAttribute(reinterpret_cast<const void*>(&gemm8<0, 9, 2304, 768>),
                            hipFuncAttributeMaxDynamicSharedMemorySize, 131072);
  (void)hipFuncSetAttribute(reinterpret_cast<const void*>(&gemm8<1, 3, 768, 768>),
                            hipFuncAttributeMaxDynamicSharedMemorySize, 131072);
  (void)hipFuncSetAttribute(reinterpret_cast<const void*>(&gemm8<2, 12, 3072, 768>),
                            hipFuncAttributeMaxDynamicSharedMemorySize, 131072);
  (void)hipFuncSetAttribute(reinterpret_cast<const void*>(&gemm8<3, 3, 768, 3072>),
                            hipFuncAttributeMaxDynamicSharedMemorySize, 131072);
}
struct WsInit {
  WsInit() {
    (void)hipMalloc(&g_buf, WS_NEED);   // initializes runtime too
    set_gemm_attrs();
  }
};
static WsInit g_wsinit;

extern "C" void kernel_launch(void* const* d_in, const int* in_sizes, int n_in,
                              void* d_out, int out_size, void* d_ws, size_t ws_size,
                              hipStream_t stream)
{
  (void)in_sizes; (void)n_in; (void)out_size;
  static bool attrs_once = [] { set_gemm_attrs(); return true; }();
  (void)attrs_once;

  const float* x     = (const float*)d_in[0];
  const float* ln1w  = (const float*)d_in[1];
  const float* ln1b  = (const float*)d_in[2];
  const float* qkvw  = (const float*)d_in[3];
  const float* projw = (const float*)d_in[4];
  const float* projb = (const float*)d_in[5];
  const float* ln2w  = (const float*)d_in[6];
  const float* ln2b  = (const float*)d_in[7];
  const float* fc1w  = (const float*)d_in[8];
  const float* fc1b  = (const float*)d_in[9];
  const float* dww   = (const float*)d_in[10];
  const float* dwb   = (const float*)d_in[11];
  const float* fc2w  = (const float*)d_in[12];
  const float* fc2b  = (const float*)d_in[13];

  char* p = (ws_size >= WS_NEED) ? (char*)d_ws : (char*)g_buf;
  u16* WQKV  = (u16*)p;   p += (size_t)2304 * 768 * 2;
  u16* WPROJ = (u16*)p;   p += (size_t)768 * 768 * 2;
  u16* WFC1  = (u16*)p;   p += (size_t)3072 * 768 * 2;
  u16* WFC2  = (u16*)p;   p += (size_t)768 * 3072 * 2;
  u16* XN    = (u16*)p;   p += SZ_XN;    // xn1 / attn_out
  u16* QKV   = (u16*)p;   p += SZ_QKV;   // q_,k_,v  / xn2
  float* X2  = (float*)p; p += SZ_X2;    // residual after attn (fp32)
  u16* HDN   = (u16*)p;   p += SZ_HDN;   // fc1 out, conv in place
  float* KV  = (float*)p; p += SZ_KV;
  float* KS  = (float*)p; p += SZ_KS;

  cvt_f32_bf16<<<(2304*768/4 + 255)/256, 256, 0, stream>>>(qkvw, WQKV, 2304*768/4);
  cvt_f32_bf16<<<(768*768/4 + 255)/256, 256, 0, stream>>>(projw, WPROJ, 768*768/4);
  cvt_f32_bf16<<<(3072*768/4 + 255)/256, 256, 0, stream>>>(fc1w, WFC1, 3072*768/4);
  cvt_f32_bf16<<<(768*3072/4 + 255)/256, 256, 0, stream>>>(fc2w, WFC2, 768*3072/4);

  const int nz = 96 * 4096 + 96 * 64;    // KV and KS are contiguous
  zero_f32<<<(nz + 255) / 256, 256, 0, stream>>>(KV, nz);
  ln_kernel<<<NTOKENS / 4, 256, 0, stream>>>(x, ln1w, ln1b, XN);
  gemm8<0, 9, 2304, 768><<<98 * 9, 512, 131072, stream>>>(XN, WQKV, nullptr, nullptr, QKV);
  kv_reduce<<<dim3(96, 8), 256, 0, stream>>>(QKV, KV, KS);
  attn_out<<<dim3(49, 12, 8), 256, 0, stream>>>(QKV, KV, KS, XN);
  gemm8<1, 3, 768, 768><<<98 * 3, 512, 131072, stream>>>(XN, WPROJ, projb, x, X2);
  ln_kernel<<<NTOKENS / 4, 256, 0, stream>>>(X2, ln2w, ln2b, QKV);
  gemm8<2, 12, 3072, 768><<<98 * 12, 512, 131072, stream>>>(QKV, WFC1, fc1b, nullptr, HDN);
  dwconv_gelu<<<dim3(48, 128), 256, 0, stream>>>(HDN, dww, dwb);
  gemm8<3, 3, 768, 3072><<<98 * 3, 512, 131072, stream>>>(HDN, WFC2, fc2b, X2, (float*)d_out);
}

// Round 2
// 1083.624 us; speedup vs baseline: 1.2533x; 1.0280x over previous
//
#include <hip/hip_runtime.h>

typedef unsigned short u16;
typedef unsigned int u32;

typedef __bf16 bf16x8 __attribute__((ext_vector_type(8)));
typedef float f32x4 __attribute__((ext_vector_type(4)));

#define DIM 768
#define HID 3072
#define NTOK 196
#define BT 128
#define NTOKENS (BT * NTOK)   // 25088
#define MJ 3136               // FRAMES * NTOK
#define HEADS 12

// workspace layout sizes (bytes)
#define SZ_WB   ((size_t)(2304*768 + 768*768 + 3072*768 + 768*3072) * 2)  // bf16 weights
#define SZ_XN   ((size_t)NTOKENS * DIM * 2)
#define SZ_QKV  ((size_t)NTOKENS * 2304 * 2)
#define SZ_X2   ((size_t)NTOKENS * DIM * 4)
#define SZ_HDN  ((size_t)NTOKENS * HID * 2)
#define SZ_KV   ((size_t)96 * 4096 * 4)
#define SZ_KS   ((size_t)96 * 64 * 4)
#define WS_NEED (SZ_WB + SZ_XN + SZ_QKV + SZ_X2 + SZ_HDN + SZ_KV + SZ_KS)

static void* g_buf = nullptr;

__device__ __forceinline__ float b2f(u16 u) {
  union { u32 i; float f; } x; x.i = ((u32)u) << 16; return x.f;
}
__device__ __forceinline__ u16 f2b(float f) {
  u32 x = __float_as_uint(f);
  return (u16)((x + 0x7fffu + ((x >> 16) & 1u)) >> 16);
}

// async 16B global->LDS (gfx950). LDS dest = wave-uniform base + lane*16.
__device__ __forceinline__ void gload_lds16(const u16* g, u16* l) {
  __builtin_amdgcn_global_load_lds(
      (const __attribute__((address_space(1))) u32*)g,
      (__attribute__((address_space(3))) u32*)l, 16, 0, 0);
}

// ---------------- f32 -> bf16 conversion (weights) ----------------
__global__ __launch_bounds__(256) void cvt_f32_bf16(const float* __restrict__ in,
    u16* __restrict__ out, int n4)
{
  int i = blockIdx.x * 256 + threadIdx.x;
  if (i < n4) {
    float4 f = ((const float4*)in)[i];
    ushort4 r;
    r.x = f2b(f.x); r.y = f2b(f.y); r.z = f2b(f.z); r.w = f2b(f.w);
    ((ushort4*)out)[i] = r;
  }
}

// ---------------- zero-fill for KV/KS accumulators ----------------
__global__ __launch_bounds__(256) void zero_f32(float* __restrict__ p, int n) {
  int i = blockIdx.x * 256 + threadIdx.x;
  if (i < n) p[i] = 0.0f;
}

// ---------------- LayerNorm: one wave per token, fp32 in, bf16 out ---------
__global__ __launch_bounds__(256) void ln_kernel(const float* __restrict__ xin,
    const float* __restrict__ w, const float* __restrict__ b, u16* __restrict__ out)
{
  const int token = blockIdx.x * 4 + (threadIdx.x >> 6);
  const int lane = threadIdx.x & 63;
  float v[12];
  const float* x = xin + (size_t)token * DIM;
#pragma unroll
  for (int c = 0; c < 3; ++c) {
    float4 f = *(const float4*)(x + c * 256 + lane * 4);
    v[c*4+0] = f.x; v[c*4+1] = f.y; v[c*4+2] = f.z; v[c*4+3] = f.w;
  }
  float s = 0.f, sq = 0.f;
#pragma unroll
  for (int i = 0; i < 12; ++i) { s += v[i]; sq += v[i] * v[i]; }
#pragma unroll
  for (int off = 32; off > 0; off >>= 1) {
    s += __shfl_xor(s, off, 64);
    sq += __shfl_xor(sq, off, 64);
  }
  const float mean = s * (1.0f / 768.0f);
  const float var = sq * (1.0f / 768.0f) - mean * mean;
  const float rstd = rsqrtf(var + 1e-5f);
  u16* o = out + (size_t)token * DIM;
#pragma unroll
  for (int c = 0; c < 3; ++c) {
    float4 wv = *(const float4*)(w + c * 256 + lane * 4);
    float4 bv = *(const float4*)(b + c * 256 + lane * 4);
    ushort4 r;
    r.x = f2b((v[c*4+0] - mean) * rstd * wv.x + bv.x);
    r.y = f2b((v[c*4+1] - mean) * rstd * wv.y + bv.y);
    r.z = f2b((v[c*4+2] - mean) * rstd * wv.z + bv.z);
    r.w = f2b((v[c*4+3] - mean) * rstd * wv.w + bv.w);
    *(ushort4*)(o + c * 256 + lane * 4) = r;
  }
}

// ================= 256x256 4-phase MFMA GEMM (T2+T3+T4+T5) =================
// C[M,N] = A[M,K] * W[N,K]^T, fused epilogues.
// BM=BN=256, BK=64, 8 waves (2Mx4N), per-wave 128x64 output = acc[8][4].
// LDS 128 KiB dynamic: A[2][256][64] + B[2][256][64] bf16, XOR-swizzled:
//   physical byte = row*128 + (colbyte ^ ((row&7)<<4))   (involution)
// Staged via global_load_lds (linear LDS dest) with pre-swizzled global src.
// DEEP pipeline (R1): B-halves of tile t+1 staged at P0(t),P1(t); A-halves
// of tile t+2 staged at P3(t) into tile-t's buffer (legal: all tile-t
// ds_reads are register-resident past P2's closing barrier). Single counted
// gate vmcnt(4) per K-tile at P3 (A(t+2) stays in flight). Min load slack:
// 2 phases (B1), 4 phases (A halves) -- covers L2 and most of HBM latency.
// MODE 0: QKV  (relu+0.125 on cols<1536; bf16 out)
// MODE 1: PROJ (fp32 bias + fp32 residual; fp32 out)
// MODE 2: FC1  (fp32 bias; bf16 out)
// MODE 3: FC2  (fp32 bias + fp32 residual; fp32 out)
template<int MODE, int NXT, int NN, int KK>
__global__ __launch_bounds__(512, 2) void gemm8(
    const u16* __restrict__ A, const u16* __restrict__ W,
    const float* __restrict__ bias, const float* __restrict__ res,
    void* __restrict__ out)
{
  extern __shared__ char smem[];
  u16* As = (u16*)smem;                 // 2 x 16384 u16 (64 KB)
  u16* Bs = (u16*)(smem + 65536);       // 2 x 16384 u16 (64 KB)

  const int t = threadIdx.x;
  const int l = t & 63;
  const int w = t >> 6;           // wave 0..7
  const int wm = w >> 2;          // m-half 0..1
  const int wn = w & 3;           // n-quarter 0..3

  // bijective XCD swizzle (m204): consecutive wgid per XCD -> same m-panel
  constexpr int TOTAL = 98 * NXT;
  constexpr int Q8 = TOTAL >> 3;
  constexpr int R8 = TOTAL & 7;
  const int orig = blockIdx.x;
  const int xcd = orig & 7;
  const int idx = orig >> 3;
  const int wg = (xcd < R8) ? (xcd * (Q8 + 1) + idx)
                            : (R8 * (Q8 + 1) + (xcd - R8) * Q8 + idx);
  const int m0 = (wg / NXT) * 256;
  const int n0 = (wg % NXT) * 256;

  // ---- staging: linear LDS dest byte (in half) = (2w+i)*1024 + l*16
  //      -> row = (2w+i)*8 + (l>>3), colbyte = (l&7)*16
  //      pre-swizzled source col element = ((l&7)^(l>>3))*8
  const int srow = w * 16 + (l >> 3);
  const int scol = ((l & 7) ^ (l >> 3)) * 8;
  const u16* gA = A + (size_t)(m0 + srow) * KK + scol;
  const u16* gB = W + (size_t)(n0 + srow) * KK + scol;
  u16* lA = As + w * 1024;   // u16 elems; +bb*16384 +h*8192 ; +512 for i=1
  u16* lB = Bs + w * 1024;

#define STAGE_A(bb, h, kt) do { \
    const u16* g_ = gA + (size_t)(h) * 128 * KK + (size_t)(kt) * 64; \
    u16* l_ = lA + (bb) * 16384 + (h) * 8192; \
    gload_lds16(g_, l_); \
    gload_lds16(g_ + (size_t)8 * KK, l_ + 512); } while (0)
#define STAGE_B(bb, h, kt) do { \
    const u16* g_ = gB + (size_t)(h) * 128 * KK + (size_t)(kt) * 64; \
    u16* l_ = lB + (bb) * 16384 + (h) * 8192; \
    gload_lds16(g_, l_); \
    gload_lds16(g_ + (size_t)8 * KK, l_ + 512); } while (0)

  // ---- compute-side swizzled ds_read byte offsets ----
  const int lm = l & 15;
  const int qq = l >> 4;
  const int acol = (qq << 4) ^ ((l & 7) << 4);          // kk=0; kk=1 -> ^64
  const int abase = (wm * 128 + lm) * 128 + acol;       // +mq*8192 +mi*2048
  const int bbase = (wn * 64 + lm) * 128 + acol;        // +ni*2048

  f32x4 acc[8][4];
#pragma unroll
  for (int mi = 0; mi < 8; ++mi)
#pragma unroll
    for (int ni = 0; ni < 4; ++ni) acc[mi][ni] = (f32x4){0.f, 0.f, 0.f, 0.f};

  constexpr int NT = KK / 64;

  // prologue: tile0 fully + A halves of tile1; vmcnt(4) keeps A(1) in flight
  STAGE_A(0, 0, 0); STAGE_A(0, 1, 0); STAGE_B(0, 0, 0); STAGE_B(0, 1, 0);
  STAGE_A(1, 0, 1); STAGE_A(1, 1, 1);
  asm volatile("s_waitcnt vmcnt(4)" ::: "memory");
  __builtin_amdgcn_s_barrier();

  for (int ti = 0; ti < NT; ++ti) {
    const int cb = ti & 1, nb = cb ^ 1;
    const char* Ac = (const char*)As + cb * 32768;
    const char* Bc = (const char*)Bs + cb * 32768;
    bf16x8 am[4][2], b01[2][2], b23[2][2];

    // ---- P0: read A mq0 (8) + B n0,n1 (4); stage hB0(t+1) ----
#pragma unroll
    for (int mi = 0; mi < 4; ++mi) {
      const int off = abase + mi * 2048;
      am[mi][0] = *(const bf16x8*)(Ac + off);
      am[mi][1] = *(const bf16x8*)(Ac + (off ^ 64));
    }
#pragma unroll
    for (int ni = 0; ni < 2; ++ni) {
      const int off = bbase + ni * 2048;
      b01[ni][0] = *(const bf16x8*)(Bc + off);
      b01[ni][1] = *(const bf16x8*)(Bc + (off ^ 64));
    }
    if (ti + 1 < NT) STAGE_B(nb, 0, ti + 1);
    asm volatile("" ::: "memory");
    __builtin_amdgcn_s_barrier();
    asm volatile("s_waitcnt lgkmcnt(0)" ::: "memory");
    __builtin_amdgcn_s_setprio(1);
#pragma unroll
    for (int mi = 0; mi < 4; ++mi)
#pragma unroll
      for (int ni = 0; ni < 2; ++ni) {
        acc[mi][ni] = __builtin_amdgcn_mfma_f32_16x16x32_bf16(am[mi][0], b01[ni][0], acc[mi][ni], 0, 0, 0);
        acc[mi][ni] = __builtin_amdgcn_mfma_f32_16x16x32_bf16(am[mi][1], b01[ni][1], acc[mi][ni], 0, 0, 0);
      }
    __builtin_amdgcn_s_setprio(0);
    asm volatile("" ::: "memory");
    __builtin_amdgcn_s_barrier();

    // ---- P1: read B n2,n3 (4); stage hB1(t+1) ----
#pragma unroll
    for (int ni = 0; ni < 2; ++ni) {
      const int off = bbase + (ni + 2) * 2048;
      b23[ni][0] = *(const bf16x8*)(Bc + off);
      b23[ni][1] = *(const bf16x8*)(Bc + (off ^ 64));
    }
    if (ti + 1 < NT) STAGE_B(nb, 1, ti + 1);
    asm volatile("" ::: "memory");
    __builtin_amdgcn_s_barrier();
    asm volatile("s_waitcnt lgkmcnt(0)" ::: "memory");
    __builtin_amdgcn_s_setprio(1);
#pragma unroll
    for (int mi = 0; mi < 4; ++mi)
#pragma unroll
      for (int ni = 0; ni < 2; ++ni) {
        acc[mi][ni + 2] = __builtin_amdgcn_mfma_f32_16x16x32_bf16(am[mi][0], b23[ni][0], acc[mi][ni + 2], 0, 0, 0);
        acc[mi][ni + 2] = __builtin_amdgcn_mfma_f32_16x16x32_bf16(am[mi][1], b23[ni][1], acc[mi][ni + 2], 0, 0, 0);
      }
    __builtin_amdgcn_s_setprio(0);
    asm volatile("" ::: "memory");
    __builtin_amdgcn_s_barrier();

    // ---- P2: read A mq1 (8); no staging ----
#pragma unroll
    for (int mi = 0; mi < 4; ++mi) {
      const int off = abase + 8192 + mi * 2048;
      am[mi][0] = *(const bf16x8*)(Ac + off);
      am[mi][1] = *(const bf16x8*)(Ac + (off ^ 64));
    }
    asm volatile("" ::: "memory");
    __builtin_amdgcn_s_barrier();
    asm volatile("s_waitcnt lgkmcnt(0)" ::: "memory");
    __builtin_amdgcn_s_setprio(1);
#pragma unroll
    for (int mi = 0; mi < 4; ++mi)
#pragma unroll
      for (int ni = 0; ni < 2; ++ni) {
        acc[mi + 4][ni + 2] = __builtin_amdgcn_mfma_f32_16x16x32_bf16(am[mi][0], b23[ni][0], acc[mi + 4][ni + 2], 0, 0, 0);
        acc[mi + 4][ni + 2] = __builtin_amdgcn_mfma_f32_16x16x32_bf16(am[mi][1], b23[ni][1], acc[mi + 4][ni + 2], 0, 0, 0);
      }
    __builtin_amdgcn_s_setprio(0);
    asm volatile("" ::: "memory");
    __builtin_amdgcn_s_barrier();

    // ---- P3: stage hA0,hA1(t+2) into cb (tile-t LDS fully consumed);
    //      counted gate: tile t+1 fully resident, A(t+2) 4 loads in flight
    if (ti + 2 < NT) {
      STAGE_A(cb, 0, ti + 2);
      STAGE_A(cb, 1, ti + 2);
      asm volatile("s_waitcnt vmcnt(4)" ::: "memory");
    } else {
      asm volatile("s_waitcnt vmcnt(0)" ::: "memory");
    }
    __builtin_amdgcn_s_barrier();
    __builtin_amdgcn_s_setprio(1);
#pragma unroll
    for (int mi = 0; mi < 4; ++mi)
#pragma unroll
      for (int ni = 0; ni < 2; ++ni) {
        acc[mi + 4][ni] = __builtin_amdgcn_mfma_f32_16x16x32_bf16(am[mi][0], b01[ni][0], acc[mi + 4][ni], 0, 0, 0);
        acc[mi + 4][ni] = __builtin_amdgcn_mfma_f32_16x16x32_bf16(am[mi][1], b01[ni][1], acc[mi + 4][ni], 0, 0, 0);
      }
    __builtin_amdgcn_s_setprio(0);
    asm volatile("" ::: "memory");
    __builtin_amdgcn_s_barrier();
  }
#undef STAGE_A
#undef STAGE_B

  // ---- epilogue: C row = m0+wm*128+mi*16+qq*4+r, col = n0+wn*64+ni*16+lm
#pragma unroll
  for (int mi = 0; mi < 8; ++mi) {
    const int rbase = m0 + wm * 128 + mi * 16 + qq * 4;
#pragma unroll
    for (int ni = 0; ni < 4; ++ni) {
      const int col = n0 + wn * 64 + ni * 16 + lm;
      float bv = 0.f;
      if (MODE != 0) bv = bias[col];
#pragma unroll
      for (int r = 0; r < 4; ++r) {
        float v = acc[mi][ni][r];
        const size_t idxo = (size_t)(rbase + r) * NN + col;
        if (MODE == 0) {
          if (col < 1536) v = fmaxf(v, 0.0f) + 0.125f;
          ((u16*)out)[idxo] = f2b(v);
        } else if (MODE == 1) {
          ((float*)out)[idxo] = v + bv + res[idxo];
        } else if (MODE == 2) {
          ((u16*)out)[idxo] = f2b(v + bv);
        } else {
          ((float*)out)[idxo] = v + bv + res[idxo];
        }
      }
    }
  }
}

// ---------------- kv = sum_m k_ (outer) v ; ksum = sum_m k_  ----------------
__global__ __launch_bounds__(256) void kv_reduce(const u16* __restrict__ qkv,
    float* __restrict__ kv, float* __restrict__ ksum)
{
  const int bh = blockIdx.x;       // b*12+h
  const int s = blockIdx.y;        // 0..7
  const int b = bh / 12, h = bh % 12;
  __shared__ __align__(16) u16 ks[64 * 64];
  __shared__ __align__(16) u16 vs[64 * 64];
  const int t = threadIdx.x;
  const int e = t & 63;
  const int dg = (t >> 6) * 16;

  float acc[16];
#pragma unroll
  for (int j = 0; j < 16; ++j) acc[j] = 0.f;
  float ksacc = 0.f;

  for (int ch = s; ch < 49; ch += 8) {
    const size_t tokbase = (size_t)b * MJ + ch * 64;
    __syncthreads();
#pragma unroll
    for (int i = 0; i < 2; ++i) {
      int c = t + i * 256;
      int row = c >> 3, eo = (c & 7) * 8;
      const u16* base = qkv + (tokbase + row) * 2304 + h * 64 + eo;
      *(uint4*)&ks[row * 64 + eo] = *(const uint4*)(base + 768);
      *(uint4*)&vs[row * 64 + eo] = *(const uint4*)(base + 1536);
    }
    __syncthreads();
    for (int m = 0; m < 64; ++m) {
      float kf = b2f(ks[m * 64 + e]);
      ksacc += kf;
      bf16x8 v0 = *(const bf16x8*)&vs[m * 64 + dg];
      bf16x8 v1 = *(const bf16x8*)&vs[m * 64 + dg + 8];
#pragma unroll
      for (int j = 0; j < 8; ++j) {
        acc[j]     += kf * (float)v0[j];
        acc[j + 8] += kf * (float)v1[j];
      }
    }
  }
  float* dst = kv + (size_t)bh * 4096 + e * 64 + dg;
#pragma unroll
  for (int j = 0; j < 16; ++j) atomicAdd(&dst[j], acc[j]);
  if (dg == 0) atomicAdd(&ksum[bh * 64 + e], ksacc);
}

// ---------------- out = (q_ @ kv) * z ----------------
__global__ __launch_bounds__(256) void attn_out(const u16* __restrict__ qkv,
    const float* __restrict__ kv, const float* __restrict__ ksum,
    u16* __restrict__ outp)
{
  const int chunk = blockIdx.x;   // 0..48
  const int h = blockIdx.y;       // 0..11
  const int b = blockIdx.z;       // 0..7
  __shared__ float kvs[4096];
  __shared__ float kss[64];
  __shared__ float qs[4096];      // [wave][16 tok][64 e]
  const int t = threadIdx.x;
  const float* kvsrc = kv + (size_t)(b * 12 + h) * 4096;
  for (int i = t; i < 1024; i += 256)
    ((float4*)kvs)[i] = ((const float4*)kvsrc)[i];
  if (t < 64) kss[t] = ksum[(b * 12 + h) * 64 + t];
  __syncthreads();
  const int wv = t >> 6, lane = t & 63;
  float* qw = &qs[wv * 1024];
  const size_t tok0 = (size_t)b * MJ + chunk * 64 + wv * 16;
#pragma unroll
  for (int i = 0; i < 16; ++i) {
    float q = b2f(qkv[(tok0 + i) * 2304 + h * 64 + lane]);
    float pd = q * kss[lane];
#pragma unroll
    for (int off = 32; off > 0; off >>= 1) pd += __shfl_xor(pd, off, 64);
    qw[i * 64 + lane] = q * (1.0f / (pd + 1e-6f));
  }
  float o[16];
#pragma unroll
  for (int i = 0; i < 16; ++i) o[i] = 0.f;
  for (int e = 0; e < 64; ++e) {
    const float kvc = kvs[e * 64 + lane];
#pragma unroll
    for (int i = 0; i < 16; ++i) o[i] += qw[i * 64 + e] * kvc;
  }
#pragma unroll
  for (int i = 0; i < 16; ++i)
    outp[(tok0 + i) * 768 + h * 64 + lane] = f2b(o[i]);
}

// -------- depthwise 3x3 conv + exact GELU, in place (vectorized R1) --------
// 128 channels/block (24 x 128 grid), 4 channels/lane, uint4 staging,
// ushort4 tap reads + stores. LDS row stride 136 u16 (spreads bank pairs).
__global__ __launch_bounds__(256) void dwconv_gelu(u16* __restrict__ hdn,
    const float* __restrict__ w, const float* __restrict__ bias)
{
  __shared__ u16 pl[196 * 136];
  const int cb = blockIdx.x;     // 0..23
  const int fr = blockIdx.y;     // 0..127
  const int t = threadIdx.x;
  const int c0 = cb * 128;
  u16* base = hdn + (size_t)fr * 196 * HID + c0;
  // stage 196 x 128 u16 = 3136 uint4
#pragma unroll
  for (int i = 0; i < 13; ++i) {
    int idx = i * 256 + t;
    if (idx < 3136) {
      int p = idx >> 4, cq = idx & 15;
      *(uint4*)&pl[p * 136 + cq * 8] = *(const uint4*)(base + (size_t)p * HID + cq * 8);
    }
  }
  __syncthreads();
  const int pc = t & 31;           // channel quad: c = c0 + pc*4
  const int pg = t >> 5;           // position group 0..7
  const int cc = pc * 4;
  float wr[36];
#pragma unroll
  for (int k = 0; k < 9; ++k)
#pragma unroll
    for (int u = 0; u < 4; ++u) wr[k * 4 + u] = w[(c0 + cc + u) * 9 + k];
  float bv[4];
#pragma unroll
  for (int u = 0; u < 4; ++u) bv[u] = bias[c0 + cc + u];

  for (int j = 0; j < 25; ++j) {
    const int p = pg + j * 8;
    if (p >= 196) break;
    const int py = p / 14, px = p % 14;
    float a0 = bv[0], a1 = bv[1], a2 = bv[2], a3 = bv[3];
#pragma unroll
    for (int ky = 0; ky < 3; ++ky) {
      int yy = py + ky - 1;
      if (yy < 0 || yy > 13) continue;
#pragma unroll
      for (int kx = 0; kx < 3; ++kx) {
        int xx = px + kx - 1;
        if (xx < 0 || xx > 13) continue;
        ushort4 tv = *(const ushort4*)&pl[(yy * 14 + xx) * 136 + cc];
        const float* wk = &wr[(ky * 3 + kx) * 4];
        a0 += wk[0] * b2f(tv.x);
        a1 += wk[1] * b2f(tv.y);
        a2 += wk[2] * b2f(tv.z);
        a3 += wk[3] * b2f(tv.w);
      }
    }
    ushort4 r;
    r.x = f2b(0.5f * a0 * (1.0f + erff(a0 * 0.70710678118654752f)));
    r.y = f2b(0.5f * a1 * (1.0f + erff(a1 * 0.70710678118654752f)));
    r.z = f2b(0.5f * a2 * (1.0f + erff(a2 * 0.70710678118654752f)));
    r.w = f2b(0.5f * a3 * (1.0f + erff(a3 * 0.70710678118654752f)));
    *(ushort4*)(base + (size_t)p * HID + cc) = r;
  }
}

// ---- dynamic-LDS attribute (128 KiB > 64 KiB default) + fallback buffer ----
static void set_gemm_attrs() {
  (void)hipFuncSetAttribute(reinterpret_cast<const void*>(&gemm8<0, 9, 2304, 768>),
                            hipFuncAttributeMaxDynamicSharedMemorySize, 131072);
  (void)hipFuncSetAttribute(reinterpret_cast<const void*>(&gemm8<1, 3, 768, 768>),
                            hipFuncAttributeMaxDynamicSharedMemorySize, 131072);
  (void)hipFuncSetAttribute(reinterpret_cast<const void*>(&gemm8<2, 12, 3072, 768>),
                            hipFuncAttributeMaxDynamicSharedMemorySize, 131072);
  (void)hipFuncSetAttribute(reinterpret_cast<const void*>(&gemm8<3, 3, 768, 3072>),
                            hipFuncAttributeMaxDynamicSharedMemorySize, 131072);
}
struct WsInit {
  WsInit() {
    (void)hipMalloc(&g_buf, WS_NEED);   // initializes runtime too
    set_gemm_attrs();
  }
};
static WsInit g_wsinit;

extern "C" void kernel_launch(void* const* d_in, const int* in_sizes, int n_in,
                              void* d_out, int out_size, void* d_ws, size_t ws_size,
                              hipStream_t stream)
{
  (void)in_sizes; (void)n_in; (void)out_size;
  static bool attrs_once = [] { set_gemm_attrs(); return true; }();
  (void)attrs_once;

  const float* x     = (const float*)d_in[0];
  const float* ln1w  = (const float*)d_in[1];
  const float* ln1b  = (const float*)d_in[2];
  const float* qkvw  = (const float*)d_in[3];
  const float* projw = (const float*)d_in[4];
  const float* projb = (const float*)d_in[5];
  const float* ln2w  = (const float*)d_in[6];
  const float* ln2b  = (const float*)d_in[7];
  const float* fc1w  = (const float*)d_in[8];
  const float* fc1b  = (const float*)d_in[9];
  const float* dww   = (const float*)d_in[10];
  const float* dwb   = (const float*)d_in[11];
  const float* fc2w  = (const float*)d_in[12];
  const float* fc2b  = (const float*)d_in[13];

  char* p = (ws_size >= WS_NEED) ? (char*)d_ws : (char*)g_buf;
  u16* WQKV  = (u16*)p;   p += (size_t)2304 * 768 * 2;
  u16* WPROJ = (u16*)p;   p += (size_t)768 * 768 * 2;
  u16* WFC1  = (u16*)p;   p += (size_t)3072 * 768 * 2;
  u16* WFC2  = (u16*)p;   p += (size_t)768 * 3072 * 2;
  u16* XN    = (u16*)p;   p += SZ_XN;    // xn1 / attn_out
  u16* QKV   = (u16*)p;   p += SZ_QKV;   // q_,k_,v  / xn2
  float* X2  = (float*)p; p += SZ_X2;    // residual after attn (fp32)
  u16* HDN   = (u16*)p;   p += SZ_HDN;   // fc1 out, conv in place
  float* KV  = (float*)p; p += SZ_KV;
  float* KS  = (float*)p; p += SZ_KS;

  cvt_f32_bf16<<<(2304*768/4 + 255)/256, 256, 0, stream>>>(qkvw, WQKV, 2304*768/4);
  cvt_f32_bf16<<<(768*768/4 + 255)/256, 256, 0, stream>>>(projw, WPROJ, 768*768/4);
  cvt_f32_bf16<<<(3072*768/4 + 255)/256, 256, 0, stream>>>(fc1w, WFC1, 3072*768/4);
  cvt_f32_bf16<<<(768*3072/4 + 255)/256, 256, 0, stream>>>(fc2w, WFC2, 768*3072/4);

  const int nz = 96 * 4096 + 96 * 64;    // KV and KS are contiguous
  zero_f32<<<(nz + 255) / 256, 256, 0, stream>>>(KV, nz);
  ln_kernel<<<NTOKENS / 4, 256, 0, stream>>>(x, ln1w, ln1b, XN);
  gemm8<0, 9, 2304, 768><<<98 * 9, 512, 131072, stream>>>(XN, WQKV, nullptr, nullptr, QKV);
  kv_reduce<<<dim3(96, 8), 256, 0, stream>>>(QKV, KV, KS);
  attn_out<<<dim3(49, 12, 8), 256, 0, stream>>>(QKV, KV, KS, XN);
  gemm8<1, 3, 768, 768><<<98 * 3, 512, 131072, stream>>>(XN, WPROJ, projb, x, X2);
  ln_kernel<<<NTOKENS / 4, 256, 0, stream>>>(X2, ln2w, ln2b, QKV);
  gemm8<2, 12, 3072, 768><<<98 * 12, 512, 131072, stream>>>(QKV, WFC1, fc1b, nullptr, HDN);
  dwconv_gelu<<<dim3(24, 128), 256, 0, stream>>>(HDN, dww, dwb);
  gemm8<3, 3, 768, 3072><<<98 * 3, 512, 131072, stream>>>(HDN, WFC2, fc2b, X2, (float*)d_out);
}

// Round 3
// 1066.595 us; speedup vs baseline: 1.2733x; 1.0160x over previous
//
#include <hip/hip_runtime.h>

typedef unsigned short u16;
typedef unsigned int u32;

typedef __bf16 bf16x8 __attribute__((ext_vector_type(8)));
typedef float f32x4 __attribute__((ext_vector_type(4)));

#define DIM 768
#define HID 3072
#define NTOK 196
#define BT 128
#define NTOKENS (BT * NTOK)   // 25088
#define MJ 3136               // FRAMES * NTOK
#define HEADS 12

// workspace layout sizes (bytes)
#define SZ_WB   ((size_t)(2304*768 + 768*768 + 3072*768 + 768*3072) * 2)  // bf16 weights
#define SZ_XN   ((size_t)NTOKENS * DIM * 2)
#define SZ_QKV  ((size_t)NTOKENS * 2304 * 2)
#define SZ_X2   ((size_t)NTOKENS * DIM * 4)
#define SZ_HDN  ((size_t)NTOKENS * HID * 2)
#define SZ_KV   ((size_t)96 * 4096 * 4)
#define SZ_KS   ((size_t)96 * 64 * 4)
#define WS_NEED (SZ_WB + SZ_XN + SZ_QKV + SZ_X2 + SZ_HDN + SZ_KV + SZ_KS)

static void* g_buf = nullptr;

__device__ __forceinline__ float b2f(u16 u) {
  union { u32 i; float f; } x; x.i = ((u32)u) << 16; return x.f;
}
__device__ __forceinline__ u16 f2b(float f) {
  u32 x = __float_as_uint(f);
  return (u16)((x + 0x7fffu + ((x >> 16) & 1u)) >> 16);
}

// async 16B global->LDS (gfx950). LDS dest = wave-uniform base + lane*16.
__device__ __forceinline__ void gload_lds16(const u16* g, u16* l) {
  __builtin_amdgcn_global_load_lds(
      (const __attribute__((address_space(1))) u32*)g,
      (__attribute__((address_space(3))) u32*)l, 16, 0, 0);
}

// ---------------- f32 -> bf16 conversion (weights) ----------------
__global__ __launch_bounds__(256) void cvt_f32_bf16(const float* __restrict__ in,
    u16* __restrict__ out, int n4)
{
  int i = blockIdx.x * 256 + threadIdx.x;
  if (i < n4) {
    float4 f = ((const float4*)in)[i];
    ushort4 r;
    r.x = f2b(f.x); r.y = f2b(f.y); r.z = f2b(f.z); r.w = f2b(f.w);
    ((ushort4*)out)[i] = r;
  }
}

// ---------------- zero-fill for KV/KS accumulators ----------------
__global__ __launch_bounds__(256) void zero_f32(float* __restrict__ p, int n) {
  int i = blockIdx.x * 256 + threadIdx.x;
  if (i < n) p[i] = 0.0f;
}

// ---------------- LayerNorm: one wave per token, fp32 in, bf16 out ---------
__global__ __launch_bounds__(256) void ln_kernel(const float* __restrict__ xin,
    const float* __restrict__ w, const float* __restrict__ b, u16* __restrict__ out)
{
  const int token = blockIdx.x * 4 + (threadIdx.x >> 6);
  const int lane = threadIdx.x & 63;
  float v[12];
  const float* x = xin + (size_t)token * DIM;
#pragma unroll
  for (int c = 0; c < 3; ++c) {
    float4 f = *(const float4*)(x + c * 256 + lane * 4);
    v[c*4+0] = f.x; v[c*4+1] = f.y; v[c*4+2] = f.z; v[c*4+3] = f.w;
  }
  float s = 0.f, sq = 0.f;
#pragma unroll
  for (int i = 0; i < 12; ++i) { s += v[i]; sq += v[i] * v[i]; }
#pragma unroll
  for (int off = 32; off > 0; off >>= 1) {
    s += __shfl_xor(s, off, 64);
    sq += __shfl_xor(sq, off, 64);
  }
  const float mean = s * (1.0f / 768.0f);
  const float var = sq * (1.0f / 768.0f) - mean * mean;
  const float rstd = rsqrtf(var + 1e-5f);
  u16* o = out + (size_t)token * DIM;
#pragma unroll
  for (int c = 0; c < 3; ++c) {
    float4 wv = *(const float4*)(w + c * 256 + lane * 4);
    float4 bv = *(const float4*)(b + c * 256 + lane * 4);
    ushort4 r;
    r.x = f2b((v[c*4+0] - mean) * rstd * wv.x + bv.x);
    r.y = f2b((v[c*4+1] - mean) * rstd * wv.y + bv.y);
    r.z = f2b((v[c*4+2] - mean) * rstd * wv.z + bv.z);
    r.w = f2b((v[c*4+3] - mean) * rstd * wv.w + bv.w);
    *(ushort4*)(o + c * 256 + lane * 4) = r;
  }
}

// ============ 256x256 MFMA GEMM, 2-barrier K-tile (R2 restructure) =========
// C[M,N] = A[M,K] * W[N,K]^T, fused epilogues.
// BM=BN=256, BK=64, 8 waves (2Mx4N), per-wave 128x64 output = acc[8][4].
// LDS 128 KiB dynamic, XOR-swizzled (byte ^= ((row&7)<<4)), staged via
// global_load_lds with pre-swizzled global source.
// R2: only TWO barriers per K-tile (hazard-proven):
//   body: {read mq0,n01 | stage hB0(t+1) | MFMA Q00 | read n23 |
//          stage hB1(t+1) | MFMA Q01 | read mq1 | MFMA Q11}
//   lgkm(0); barrier(a)   <- all cb-A reads complete
//   stage A(t+2) into cb  (overwrite now safe); MFMA Q10 (regs only)
//   vmcnt(4); barrier(b)  <- B(t+1)+A(t+1) landed, A(t+2) stays in flight
// Compiler inserts precise counted lgkm waits for ds_read->MFMA deps.
// MODE 0: QKV  (relu+0.125 on cols<1536; bf16 out)
// MODE 1: PROJ (fp32 bias + fp32 residual; fp32 out)
// MODE 2: FC1  (fp32 bias; bf16 out)
// MODE 3: FC2  (fp32 bias + fp32 residual; fp32 out)
template<int MODE, int NXT, int NN, int KK>
__global__ __launch_bounds__(512, 2) void gemm8(
    const u16* __restrict__ A, const u16* __restrict__ W,
    const float* __restrict__ bias, const float* __restrict__ res,
    void* __restrict__ out)
{
  extern __shared__ char smem[];
  u16* As = (u16*)smem;                 // 2 x 16384 u16 (64 KB)
  u16* Bs = (u16*)(smem + 65536);       // 2 x 16384 u16 (64 KB)

  const int t = threadIdx.x;
  const int l = t & 63;
  const int w = t >> 6;           // wave 0..7
  const int wm = w >> 2;          // m-half 0..1
  const int wn = w & 3;           // n-quarter 0..3

  // bijective XCD swizzle (m204)
  constexpr int TOTAL = 98 * NXT;
  constexpr int Q8 = TOTAL >> 3;
  constexpr int R8 = TOTAL & 7;
  const int orig = blockIdx.x;
  const int xcd = orig & 7;
  const int idx = orig >> 3;
  const int wg = (xcd < R8) ? (xcd * (Q8 + 1) + idx)
                            : (R8 * (Q8 + 1) + (xcd - R8) * Q8 + idx);
  const int m0 = (wg / NXT) * 256;
  const int n0 = (wg % NXT) * 256;

  // ---- staging addresses (linear LDS dest, pre-swizzled global source) ----
  const int srow = w * 16 + (l >> 3);
  const int scol = ((l & 7) ^ (l >> 3)) * 8;
  const u16* gA = A + (size_t)(m0 + srow) * KK + scol;
  const u16* gB = W + (size_t)(n0 + srow) * KK + scol;
  u16* lA = As + w * 1024;
  u16* lB = Bs + w * 1024;

#define STAGE_A(bb, h, kt) do { \
    const u16* g_ = gA + (size_t)(h) * 128 * KK + (size_t)(kt) * 64; \
    u16* l_ = lA + (bb) * 16384 + (h) * 8192; \
    gload_lds16(g_, l_); \
    gload_lds16(g_ + (size_t)8 * KK, l_ + 512); } while (0)
#define STAGE_B(bb, h, kt) do { \
    const u16* g_ = gB + (size_t)(h) * 128 * KK + (size_t)(kt) * 64; \
    u16* l_ = lB + (bb) * 16384 + (h) * 8192; \
    gload_lds16(g_, l_); \
    gload_lds16(g_ + (size_t)8 * KK, l_ + 512); } while (0)

  // ---- compute-side swizzled ds_read byte offsets ----
  const int lm = l & 15;
  const int qq = l >> 4;
  const int acol = (qq << 4) ^ ((l & 7) << 4);          // kk=0; kk=1 -> ^64
  const int abase = (wm * 128 + lm) * 128 + acol;       // +mq*8192 +mi*2048
  const int bbase = (wn * 64 + lm) * 128 + acol;        // +ni*2048

  f32x4 acc[8][4];
#pragma unroll
  for (int mi = 0; mi < 8; ++mi)
#pragma unroll
    for (int ni = 0; ni < 4; ++ni) acc[mi][ni] = (f32x4){0.f, 0.f, 0.f, 0.f};

  constexpr int NT = KK / 64;

  // prologue: tile0 fully + A halves of tile1; vmcnt(4) keeps A(1) in flight
  STAGE_A(0, 0, 0); STAGE_A(0, 1, 0); STAGE_B(0, 0, 0); STAGE_B(0, 1, 0);
  STAGE_A(1, 0, 1); STAGE_A(1, 1, 1);
  asm volatile("s_waitcnt vmcnt(4)" ::: "memory");
  __builtin_amdgcn_s_barrier();

  for (int ti = 0; ti < NT; ++ti) {
    const int cb = ti & 1, nb = cb ^ 1;
    const char* Ac = (const char*)As + cb * 32768;
    const char* Bc = (const char*)Bs + cb * 32768;
    bf16x8 a0[4][2], a1[4][2], b01[2][2], b23[2][2];

    // reads: A mq0 (8) + B n01 (4); stage hB0(t+1)
#pragma unroll
    for (int mi = 0; mi < 4; ++mi) {
      const int off = abase + mi * 2048;
      a0[mi][0] = *(const bf16x8*)(Ac + off);
      a0[mi][1] = *(const bf16x8*)(Ac + (off ^ 64));
    }
#pragma unroll
    for (int ni = 0; ni < 2; ++ni) {
      const int off = bbase + ni * 2048;
      b01[ni][0] = *(const bf16x8*)(Bc + off);
      b01[ni][1] = *(const bf16x8*)(Bc + (off ^ 64));
    }
    if (ti + 1 < NT) STAGE_B(nb, 0, ti + 1);
    __builtin_amdgcn_s_setprio(1);
#pragma unroll
    for (int mi = 0; mi < 4; ++mi)
#pragma unroll
      for (int ni = 0; ni < 2; ++ni) {
        acc[mi][ni] = __builtin_amdgcn_mfma_f32_16x16x32_bf16(a0[mi][0], b01[ni][0], acc[mi][ni], 0, 0, 0);
        acc[mi][ni] = __builtin_amdgcn_mfma_f32_16x16x32_bf16(a0[mi][1], b01[ni][1], acc[mi][ni], 0, 0, 0);
      }
    __builtin_amdgcn_s_setprio(0);

    // reads: B n23 (4); stage hB1(t+1)
#pragma unroll
    for (int ni = 0; ni < 2; ++ni) {
      const int off = bbase + (ni + 2) * 2048;
      b23[ni][0] = *(const bf16x8*)(Bc + off);
      b23[ni][1] = *(const bf16x8*)(Bc + (off ^ 64));
    }
    if (ti + 1 < NT) STAGE_B(nb, 1, ti + 1);
    __builtin_amdgcn_s_setprio(1);
#pragma unroll
    for (int mi = 0; mi < 4; ++mi)
#pragma unroll
      for (int ni = 0; ni < 2; ++ni) {
        acc[mi][ni + 2] = __builtin_amdgcn_mfma_f32_16x16x32_bf16(a0[mi][0], b23[ni][0], acc[mi][ni + 2], 0, 0, 0);
        acc[mi][ni + 2] = __builtin_amdgcn_mfma_f32_16x16x32_bf16(a0[mi][1], b23[ni][1], acc[mi][ni + 2], 0, 0, 0);
      }
    __builtin_amdgcn_s_setprio(0);

    // reads: A mq1 (8)
#pragma unroll
    for (int mi = 0; mi < 4; ++mi) {
      const int off = abase + 8192 + mi * 2048;
      a1[mi][0] = *(const bf16x8*)(Ac + off);
      a1[mi][1] = *(const bf16x8*)(Ac + (off ^ 64));
    }
    __builtin_amdgcn_s_setprio(1);
#pragma unroll
    for (int mi = 0; mi < 4; ++mi)
#pragma unroll
      for (int ni = 0; ni < 2; ++ni) {
        acc[mi + 4][ni + 2] = __builtin_amdgcn_mfma_f32_16x16x32_bf16(a1[mi][0], b23[ni][0], acc[mi + 4][ni + 2], 0, 0, 0);
        acc[mi + 4][ni + 2] = __builtin_amdgcn_mfma_f32_16x16x32_bf16(a1[mi][1], b23[ni][1], acc[mi + 4][ni + 2], 0, 0, 0);
      }
    __builtin_amdgcn_s_setprio(0);

    // barrier (a): all waves' cb-A reads complete -> cb-A may be overwritten
    asm volatile("s_waitcnt lgkmcnt(0)" ::: "memory");
    __builtin_amdgcn_s_barrier();

    if (ti + 2 < NT) { STAGE_A(cb, 0, ti + 2); STAGE_A(cb, 1, ti + 2); }

    __builtin_amdgcn_s_setprio(1);
#pragma unroll
    for (int mi = 0; mi < 4; ++mi)
#pragma unroll
      for (int ni = 0; ni < 2; ++ni) {
        acc[mi + 4][ni] = __builtin_amdgcn_mfma_f32_16x16x32_bf16(a1[mi][0], b01[ni][0], acc[mi + 4][ni], 0, 0, 0);
        acc[mi + 4][ni] = __builtin_amdgcn_mfma_f32_16x16x32_bf16(a1[mi][1], b01[ni][1], acc[mi + 4][ni], 0, 0, 0);
      }
    __builtin_amdgcn_s_setprio(0);

    // barrier (b): tile t+1 fully landed; A(t+2) (newest 4 loads) in flight
    if (ti + 2 < NT) {
      asm volatile("s_waitcnt vmcnt(4)" ::: "memory");
    } else {
      asm volatile("s_waitcnt vmcnt(0)" ::: "memory");
    }
    __builtin_amdgcn_s_barrier();
  }
#undef STAGE_A
#undef STAGE_B

  // ---- epilogue: C row = m0+wm*128+mi*16+qq*4+r, col = n0+wn*64+ni*16+lm
#pragma unroll
  for (int mi = 0; mi < 8; ++mi) {
    const int rbase = m0 + wm * 128 + mi * 16 + qq * 4;
#pragma unroll
    for (int ni = 0; ni < 4; ++ni) {
      const int col = n0 + wn * 64 + ni * 16 + lm;
      float bv = 0.f;
      if (MODE != 0) bv = bias[col];
#pragma unroll
      for (int r = 0; r < 4; ++r) {
        float v = acc[mi][ni][r];
        const size_t idxo = (size_t)(rbase + r) * NN + col;
        if (MODE == 0) {
          if (col < 1536) v = fmaxf(v, 0.0f) + 0.125f;
          ((u16*)out)[idxo] = f2b(v);
        } else if (MODE == 1) {
          ((float*)out)[idxo] = v + bv + res[idxo];
        } else if (MODE == 2) {
          ((u16*)out)[idxo] = f2b(v + bv);
        } else {
          ((float*)out)[idxo] = v + bv + res[idxo];
        }
      }
    }
  }
}

// ---------------- kv = sum_m k_ (outer) v ; ksum = sum_m k_  ----------------
__global__ __launch_bounds__(256) void kv_reduce(const u16* __restrict__ qkv,
    float* __restrict__ kv, float* __restrict__ ksum)
{
  const int bh = blockIdx.x;       // b*12+h
  const int s = blockIdx.y;        // 0..7
  const int b = bh / 12, h = bh % 12;
  __shared__ __align__(16) u16 ks[64 * 64];
  __shared__ __align__(16) u16 vs[64 * 64];
  const int t = threadIdx.x;
  const int e = t & 63;
  const int dg = (t >> 6) * 16;

  float acc[16];
#pragma unroll
  for (int j = 0; j < 16; ++j) acc[j] = 0.f;
  float ksacc = 0.f;

  for (int ch = s; ch < 49; ch += 8) {
    const size_t tokbase = (size_t)b * MJ + ch * 64;
    __syncthreads();
#pragma unroll
    for (int i = 0; i < 2; ++i) {
      int c = t + i * 256;
      int row = c >> 3, eo = (c & 7) * 8;
      const u16* base = qkv + (tokbase + row) * 2304 + h * 64 + eo;
      *(uint4*)&ks[row * 64 + eo] = *(const uint4*)(base + 768);
      *(uint4*)&vs[row * 64 + eo] = *(const uint4*)(base + 1536);
    }
    __syncthreads();
    for (int m = 0; m < 64; ++m) {
      float kf = b2f(ks[m * 64 + e]);
      ksacc += kf;
      bf16x8 v0 = *(const bf16x8*)&vs[m * 64 + dg];
      bf16x8 v1 = *(const bf16x8*)&vs[m * 64 + dg + 8];
#pragma unroll
      for (int j = 0; j < 8; ++j) {
        acc[j]     += kf * (float)v0[j];
        acc[j + 8] += kf * (float)v1[j];
      }
    }
  }
  float* dst = kv + (size_t)bh * 4096 + e * 64 + dg;
#pragma unroll
  for (int j = 0; j < 16; ++j) atomicAdd(&dst[j], acc[j]);
  if (dg == 0) atomicAdd(&ksum[bh * 64 + e], ksacc);
}

// ---------------- out = (q_ @ kv) * z ----------------
__global__ __launch_bounds__(256) void attn_out(const u16* __restrict__ qkv,
    const float* __restrict__ kv, const float* __restrict__ ksum,
    u16* __restrict__ outp)
{
  const int chunk = blockIdx.x;   // 0..48
  const int h = blockIdx.y;       // 0..11
  const int b = blockIdx.z;       // 0..7
  __shared__ float kvs[4096];
  __shared__ float kss[64];
  __shared__ float qs[4096];      // [wave][16 tok][64 e]
  const int t = threadIdx.x;
  const float* kvsrc = kv + (size_t)(b * 12 + h) * 4096;
  for (int i = t; i < 1024; i += 256)
    ((float4*)kvs)[i] = ((const float4*)kvsrc)[i];
  if (t < 64) kss[t] = ksum[(b * 12 + h) * 64 + t];
  __syncthreads();
  const int wv = t >> 6, lane = t & 63;
  float* qw = &qs[wv * 1024];
  const size_t tok0 = (size_t)b * MJ + chunk * 64 + wv * 16;
#pragma unroll
  for (int i = 0; i < 16; ++i) {
    float q = b2f(qkv[(tok0 + i) * 2304 + h * 64 + lane]);
    float pd = q * kss[lane];
#pragma unroll
    for (int off = 32; off > 0; off >>= 1) pd += __shfl_xor(pd, off, 64);
    qw[i * 64 + lane] = q * (1.0f / (pd + 1e-6f));
  }
  float o[16];
#pragma unroll
  for (int i = 0; i < 16; ++i) o[i] = 0.f;
  for (int e = 0; e < 64; ++e) {
    const float kvc = kvs[e * 64 + lane];
#pragma unroll
    for (int i = 0; i < 16; ++i) o[i] += qw[i * 64 + e] * kvc;
  }
#pragma unroll
  for (int i = 0; i < 16; ++i)
    outp[(tok0 + i) * 768 + h * 64 + lane] = f2b(o[i]);
}

// -------- depthwise 3x3 conv + exact GELU, in place (vectorized) --------
__global__ __launch_bounds__(256) void dwconv_gelu(u16* __restrict__ hdn,
    const float* __restrict__ w, const float* __restrict__ bias)
{
  __shared__ u16 pl[196 * 136];
  const int cb = blockIdx.x;     // 0..23
  const int fr = blockIdx.y;     // 0..127
  const int t = threadIdx.x;
  const int c0 = cb * 128;
  u16* base = hdn + (size_t)fr * 196 * HID + c0;
#pragma unroll
  for (int i = 0; i < 13; ++i) {
    int idx = i * 256 + t;
    if (idx < 3136) {
      int p = idx >> 4, cq = idx & 15;
      *(uint4*)&pl[p * 136 + cq * 8] = *(const uint4*)(base + (size_t)p * HID + cq * 8);
    }
  }
  __syncthreads();
  const int pc = t & 31;           // channel quad: c = c0 + pc*4
  const int pg = t >> 5;           // position group 0..7
  const int cc = pc * 4;
  float wr[36];
#pragma unroll
  for (int k = 0; k < 9; ++k)
#pragma unroll
    for (int u = 0; u < 4; ++u) wr[k * 4 + u] = w[(c0 + cc + u) * 9 + k];
  float bv[4];
#pragma unroll
  for (int u = 0; u < 4; ++u) bv[u] = bias[c0 + cc + u];

  for (int j = 0; j < 25; ++j) {
    const int p = pg + j * 8;
    if (p >= 196) break;
    const int py = p / 14, px = p % 14;
    float a0 = bv[0], a1 = bv[1], a2 = bv[2], a3 = bv[3];
#pragma unroll
    for (int ky = 0; ky < 3; ++ky) {
      int yy = py + ky - 1;
      if (yy < 0 || yy > 13) continue;
#pragma unroll
      for (int kx = 0; kx < 3; ++kx) {
        int xx = px + kx - 1;
        if (xx < 0 || xx > 13) continue;
        ushort4 tv = *(const ushort4*)&pl[(yy * 14 + xx) * 136 + cc];
        const float* wk = &wr[(ky * 3 + kx) * 4];
        a0 += wk[0] * b2f(tv.x);
        a1 += wk[1] * b2f(tv.y);
        a2 += wk[2] * b2f(tv.z);
        a3 += wk[3] * b2f(tv.w);
      }
    }
    ushort4 r;
    r.x = f2b(0.5f * a0 * (1.0f + erff(a0 * 0.70710678118654752f)));
    r.y = f2b(0.5f * a1 * (1.0f + erff(a1 * 0.70710678118654752f)));
    r.z = f2b(0.5f * a2 * (1.0f + erff(a2 * 0.70710678118654752f)));
    r.w = f2b(0.5f * a3 * (1.0f + erff(a3 * 0.70710678118654752f)));
    *(ushort4*)(base + (size_t)p * HID + cc) = r;
  }
}

// ---- dynamic-LDS attribute (128 KiB > 64 KiB default) + fallback buffer ----
static void set_gemm_attrs() {
  (void)hipFuncSetAttribute(reinterpret_cast<const void*>(&gemm8<0, 9, 2304, 768>),
                            hipFuncAttributeMaxDynamicSharedMemorySize, 131072);
  (void)hipFuncSetAttribute(reinterpret_cast<const void*>(&gemm8<1, 3, 768, 768>),
                            hipFuncAttributeMaxDynamicSharedMemorySize, 131072);
  (void)hipFuncSetAttribute(reinterpret_cast<const void*>(&gemm8<2, 12, 3072, 768>),
                            hipFuncAttributeMaxDynamicSharedMemorySize, 131072);
  (void)hipFuncSetAttribute(reinterpret_cast<const void*>(&gemm8<3, 3, 768, 3072>),
                            hipFuncAttributeMaxDynamicSharedMemorySize, 131072);
}
struct WsInit {
  WsInit() {
    (void)hipMalloc(&g_buf, WS_NEED);   // initializes runtime too
    set_gemm_attrs();
  }
};
static WsInit g_wsinit;

extern "C" void kernel_launch(void* const* d_in, const int* in_sizes, int n_in,
                              void* d_out, int out_size, void* d_ws, size_t ws_size,
                              hipStream_t stream)
{
  (void)in_sizes; (void)n_in; (void)out_size;
  static bool attrs_once = [] { set_gemm_attrs(); return true; }();
  (void)attrs_once;

  const float* x     = (const float*)d_in[0];
  const float* ln1w  = (const float*)d_in[1];
  const float* ln1b  = (const float*)d_in[2];
  const float* qkvw  = (const float*)d_in[3];
  const float* projw = (const float*)d_in[4];
  const float* projb = (const float*)d_in[5];
  const float* ln2w  = (const float*)d_in[6];
  const float* ln2b  = (const float*)d_in[7];
  const float* fc1w  = (const float*)d_in[8];
  const float* fc1b  = (const float*)d_in[9];
  const float* dww   = (const float*)d_in[10];
  const float* dwb   = (const float*)d_in[11];
  const float* fc2w  = (const float*)d_in[12];
  const float* fc2b  = (const float*)d_in[13];

  char* p = (ws_size >= WS_NEED) ? (char*)d_ws : (char*)g_buf;
  u16* WQKV  = (u16*)p;   p += (size_t)2304 * 768 * 2;
  u16* WPROJ = (u16*)p;   p += (size_t)768 * 768 * 2;
  u16* WFC1  = (u16*)p;   p += (size_t)3072 * 768 * 2;
  u16* WFC2  = (u16*)p;   p += (size_t)768 * 3072 * 2;
  u16* XN    = (u16*)p;   p += SZ_XN;    // xn1 / attn_out
  u16* QKV   = (u16*)p;   p += SZ_QKV;   // q_,k_,v  / xn2
  float* X2  = (float*)p; p += SZ_X2;    // residual after attn (fp32)
  u16* HDN   = (u16*)p;   p += SZ_HDN;   // fc1 out, conv in place
  float* KV  = (float*)p; p += SZ_KV;
  float* KS  = (float*)p; p += SZ_KS;

  cvt_f32_bf16<<<(2304*768/4 + 255)/256, 256, 0, stream>>>(qkvw, WQKV, 2304*768/4);
  cvt_f32_bf16<<<(768*768/4 + 255)/256, 256, 0, stream>>>(projw, WPROJ, 768*768/4);
  cvt_f32_bf16<<<(3072*768/4 + 255)/256, 256, 0, stream>>>(fc1w, WFC1, 3072*768/4);
  cvt_f32_bf16<<<(768*3072/4 + 255)/256, 256, 0, stream>>>(fc2w, WFC2, 768*3072/4);

  const int nz = 96 * 4096 + 96 * 64;    // KV and KS are contiguous
  zero_f32<<<(nz + 255) / 256, 256, 0, stream>>>(KV, nz);
  ln_kernel<<<NTOKENS / 4, 256, 0, stream>>>(x, ln1w, ln1b, XN);
  gemm8<0, 9, 2304, 768><<<98 * 9, 512, 131072, stream>>>(XN, WQKV, nullptr, nullptr, QKV);
  kv_reduce<<<dim3(96, 8), 256, 0, stream>>>(QKV, KV, KS);
  attn_out<<<dim3(49, 12, 8), 256, 0, stream>>>(QKV, KV, KS, XN);
  gemm8<1, 3, 768, 768><<<98 * 3, 512, 131072, stream>>>(XN, WPROJ, projb, x, X2);
  ln_kernel<<<NTOKENS / 4, 256, 0, stream>>>(X2, ln2w, ln2b, QKV);
  gemm8<2, 12, 3072, 768><<<98 * 12, 512, 131072, stream>>>(QKV, WFC1, fc1b, nullptr, HDN);
  dwconv_gelu<<<dim3(24, 128), 256, 0, stream>>>(HDN, dww, dwb);
  gemm8<3, 3, 768, 3072><<<98 * 3, 512, 131072, stream>>>(HDN, WFC2, fc2b, X2, (float*)d_out);
}

// Round 4
// 895.930 us; speedup vs baseline: 1.5159x; 1.1905x over previous
//
#include <hip/hip_runtime.h>

typedef unsigned short u16;
typedef unsigned int u32;

typedef __bf16 bf16x8 __attribute__((ext_vector_type(8)));
typedef float f32x4 __attribute__((ext_vector_type(4)));

#define DIM 768
#define HID 3072
#define NTOK 196
#define BT 128
#define NTOKENS (BT * NTOK)   // 25088
#define MJ 3136               // FRAMES * NTOK
#define HEADS 12

// Q / KT / VT element counts inside the QKV workspace region
#define QB_ELE ((size_t)NTOKENS * 768)        // 19267584 elems (also KT, VT size)

// workspace layout sizes (bytes)
#define SZ_WB   ((size_t)(2304*768 + 768*768 + 3072*768 + 768*3072) * 2)  // bf16 weights
#define SZ_XN   ((size_t)NTOKENS * DIM * 2)
#define SZ_QKV  ((size_t)NTOKENS * 2304 * 2)  // Qb + KT + VT
#define SZ_X2   ((size_t)NTOKENS * DIM * 4)
#define SZ_HDN  ((size_t)NTOKENS * HID * 2)
#define SZ_KV   ((size_t)96 * 4096 * 4)
#define SZ_KS   ((size_t)96 * 64 * 4)
#define WS_NEED (SZ_WB + SZ_XN + SZ_QKV + SZ_X2 + SZ_HDN + SZ_KV + SZ_KS)

static void* g_buf = nullptr;

__device__ __forceinline__ float b2f(u16 u) {
  union { u32 i; float f; } x; x.i = ((u32)u) << 16; return x.f;
}
__device__ __forceinline__ u16 f2b(float f) {
  u32 x = __float_as_uint(f);
  return (u16)((x + 0x7fffu + ((x >> 16) & 1u)) >> 16);
}

// async 16B global->LDS (gfx950). LDS dest = wave-uniform base + lane*16.
__device__ __forceinline__ void gload_lds16(const u16* g, u16* l) {
  __builtin_amdgcn_global_load_lds(
      (const __attribute__((address_space(1))) u32*)g,
      (__attribute__((address_space(3))) u32*)l, 16, 0, 0);
}

// ---------------- f32 -> bf16 conversion (weights) ----------------
__global__ __launch_bounds__(256) void cvt_f32_bf16(const float* __restrict__ in,
    u16* __restrict__ out, int n4)
{
  int i = blockIdx.x * 256 + threadIdx.x;
  if (i < n4) {
    float4 f = ((const float4*)in)[i];
    ushort4 r;
    r.x = f2b(f.x); r.y = f2b(f.y); r.z = f2b(f.z); r.w = f2b(f.w);
    ((ushort4*)out)[i] = r;
  }
}

// ---------------- zero-fill for KV/KS accumulators ----------------
__global__ __launch_bounds__(256) void zero_f32(float* __restrict__ p, int n) {
  int i = blockIdx.x * 256 + threadIdx.x;
  if (i < n) p[i] = 0.0f;
}

// ---------------- LayerNorm: one wave per token, fp32 in, bf16 out ---------
__global__ __launch_bounds__(256) void ln_kernel(const float* __restrict__ xin,
    const float* __restrict__ w, const float* __restrict__ b, u16* __restrict__ out)
{
  const int token = blockIdx.x * 4 + (threadIdx.x >> 6);
  const int lane = threadIdx.x & 63;
  float v[12];
  const float* x = xin + (size_t)token * DIM;
#pragma unroll
  for (int c = 0; c < 3; ++c) {
    float4 f = *(const float4*)(x + c * 256 + lane * 4);
    v[c*4+0] = f.x; v[c*4+1] = f.y; v[c*4+2] = f.z; v[c*4+3] = f.w;
  }
  float s = 0.f, sq = 0.f;
#pragma unroll
  for (int i = 0; i < 12; ++i) { s += v[i]; sq += v[i] * v[i]; }
#pragma unroll
  for (int off = 32; off > 0; off >>= 1) {
    s += __shfl_xor(s, off, 64);
    sq += __shfl_xor(sq, off, 64);
  }
  const float mean = s * (1.0f / 768.0f);
  const float var = sq * (1.0f / 768.0f) - mean * mean;
  const float rstd = rsqrtf(var + 1e-5f);
  u16* o = out + (size_t)token * DIM;
#pragma unroll
  for (int c = 0; c < 3; ++c) {
    float4 wv = *(const float4*)(w + c * 256 + lane * 4);
    float4 bv = *(const float4*)(b + c * 256 + lane * 4);
    ushort4 r;
    r.x = f2b((v[c*4+0] - mean) * rstd * wv.x + bv.x);
    r.y = f2b((v[c*4+1] - mean) * rstd * wv.y + bv.y);
    r.z = f2b((v[c*4+2] - mean) * rstd * wv.z + bv.z);
    r.w = f2b((v[c*4+3] - mean) * rstd * wv.w + bv.w);
    *(ushort4*)(o + c * 256 + lane * 4) = r;
  }
}

// ============ 256x256 MFMA GEMM, 2-barrier K-tile ============
// C[M,N] = A[M,K] * W[N,K]^T, fused epilogues.
// BM=BN=256, BK=64, 8 waves (2Mx4N), per-wave 128x64 output = acc[8][4].
// LDS 128 KiB dynamic, XOR-swizzled (byte ^= ((row&7)<<4)), staged via
// global_load_lds with pre-swizzled global source. Two barriers per K-tile;
// counted vmcnt(4) keeps A(t+2) in flight across the buffer swap.
// MODE 0: QKV  (relu+0.125 on cols<1536). Scatter epilogue (R3):
//         cols<768 -> Qb[m][768]; 768..1535 -> KT[b,h][e][mj] (transposed);
//         >=1536  -> VT[b,h][d][mj] (transposed, no relu). bf16 out.
// MODE 1: PROJ (fp32 bias + fp32 residual; fp32 out)
// MODE 2: FC1  (fp32 bias; bf16 out)
// MODE 3: FC2  (fp32 bias + fp32 residual; fp32 out)
template<int MODE, int NXT, int NN, int KK>
__global__ __launch_bounds__(512, 2) void gemm8(
    const u16* __restrict__ A, const u16* __restrict__ W,
    const float* __restrict__ bias, const float* __restrict__ res,
    void* __restrict__ out)
{
  extern __shared__ char smem[];
  u16* As = (u16*)smem;                 // 2 x 16384 u16 (64 KB)
  u16* Bs = (u16*)(smem + 65536);       // 2 x 16384 u16 (64 KB)

  const int t = threadIdx.x;
  const int l = t & 63;
  const int w = t >> 6;           // wave 0..7
  const int wm = w >> 2;          // m-half 0..1
  const int wn = w & 3;           // n-quarter 0..3

  // bijective XCD swizzle (m204)
  constexpr int TOTAL = 98 * NXT;
  constexpr int Q8 = TOTAL >> 3;
  constexpr int R8 = TOTAL & 7;
  const int orig = blockIdx.x;
  const int xcd = orig & 7;
  const int idx = orig >> 3;
  const int wg = (xcd < R8) ? (xcd * (Q8 + 1) + idx)
                            : (R8 * (Q8 + 1) + (xcd - R8) * Q8 + idx);
  const int m0 = (wg / NXT) * 256;
  const int n0 = (wg % NXT) * 256;

  // ---- staging addresses (linear LDS dest, pre-swizzled global source) ----
  const int srow = w * 16 + (l >> 3);
  const int scol = ((l & 7) ^ (l >> 3)) * 8;
  const u16* gA = A + (size_t)(m0 + srow) * KK + scol;
  const u16* gB = W + (size_t)(n0 + srow) * KK + scol;
  u16* lA = As + w * 1024;
  u16* lB = Bs + w * 1024;

#define STAGE_A(bb, h, kt) do { \
    const u16* g_ = gA + (size_t)(h) * 128 * KK + (size_t)(kt) * 64; \
    u16* l_ = lA + (bb) * 16384 + (h) * 8192; \
    gload_lds16(g_, l_); \
    gload_lds16(g_ + (size_t)8 * KK, l_ + 512); } while (0)
#define STAGE_B(bb, h, kt) do { \
    const u16* g_ = gB + (size_t)(h) * 128 * KK + (size_t)(kt) * 64; \
    u16* l_ = lB + (bb) * 16384 + (h) * 8192; \
    gload_lds16(g_, l_); \
    gload_lds16(g_ + (size_t)8 * KK, l_ + 512); } while (0)

  // ---- compute-side swizzled ds_read byte offsets ----
  const int lm = l & 15;
  const int qq = l >> 4;
  const int acol = (qq << 4) ^ ((l & 7) << 4);          // kk=0; kk=1 -> ^64
  const int abase = (wm * 128 + lm) * 128 + acol;       // +mq*8192 +mi*2048
  const int bbase = (wn * 64 + lm) * 128 + acol;        // +ni*2048

  f32x4 acc[8][4];
#pragma unroll
  for (int mi = 0; mi < 8; ++mi)
#pragma unroll
    for (int ni = 0; ni < 4; ++ni) acc[mi][ni] = (f32x4){0.f, 0.f, 0.f, 0.f};

  constexpr int NT = KK / 64;

  // prologue: tile0 fully + A halves of tile1; vmcnt(4) keeps A(1) in flight
  STAGE_A(0, 0, 0); STAGE_A(0, 1, 0); STAGE_B(0, 0, 0); STAGE_B(0, 1, 0);
  STAGE_A(1, 0, 1); STAGE_A(1, 1, 1);
  asm volatile("s_waitcnt vmcnt(4)" ::: "memory");
  __builtin_amdgcn_s_barrier();

  for (int ti = 0; ti < NT; ++ti) {
    const int cb = ti & 1, nb = cb ^ 1;
    const char* Ac = (const char*)As + cb * 32768;
    const char* Bc = (const char*)Bs + cb * 32768;
    bf16x8 a0[4][2], a1[4][2], b01[2][2], b23[2][2];

    // reads: A mq0 (8) + B n01 (4); stage hB0(t+1)
#pragma unroll
    for (int mi = 0; mi < 4; ++mi) {
      const int off = abase + mi * 2048;
      a0[mi][0] = *(const bf16x8*)(Ac + off);
      a0[mi][1] = *(const bf16x8*)(Ac + (off ^ 64));
    }
#pragma unroll
    for (int ni = 0; ni < 2; ++ni) {
      const int off = bbase + ni * 2048;
      b01[ni][0] = *(const bf16x8*)(Bc + off);
      b01[ni][1] = *(const bf16x8*)(Bc + (off ^ 64));
    }
    if (ti + 1 < NT) STAGE_B(nb, 0, ti + 1);
    __builtin_amdgcn_s_setprio(1);
#pragma unroll
    for (int mi = 0; mi < 4; ++mi)
#pragma unroll
      for (int ni = 0; ni < 2; ++ni) {
        acc[mi][ni] = __builtin_amdgcn_mfma_f32_16x16x32_bf16(a0[mi][0], b01[ni][0], acc[mi][ni], 0, 0, 0);
        acc[mi][ni] = __builtin_amdgcn_mfma_f32_16x16x32_bf16(a0[mi][1], b01[ni][1], acc[mi][ni], 0, 0, 0);
      }
    __builtin_amdgcn_s_setprio(0);

    // reads: B n23 (4); stage hB1(t+1)
#pragma unroll
    for (int ni = 0; ni < 2; ++ni) {
      const int off = bbase + (ni + 2) * 2048;
      b23[ni][0] = *(const bf16x8*)(Bc + off);
      b23[ni][1] = *(const bf16x8*)(Bc + (off ^ 64));
    }
    if (ti + 1 < NT) STAGE_B(nb, 1, ti + 1);
    __builtin_amdgcn_s_setprio(1);
#pragma unroll
    for (int mi = 0; mi < 4; ++mi)
#pragma unroll
      for (int ni = 0; ni < 2; ++ni) {
        acc[mi][ni + 2] = __builtin_amdgcn_mfma_f32_16x16x32_bf16(a0[mi][0], b23[ni][0], acc[mi][ni + 2], 0, 0, 0);
        acc[mi][ni + 2] = __builtin_amdgcn_mfma_f32_16x16x32_bf16(a0[mi][1], b23[ni][1], acc[mi][ni + 2], 0, 0, 0);
      }
    __builtin_amdgcn_s_setprio(0);

    // reads: A mq1 (8)
#pragma unroll
    for (int mi = 0; mi < 4; ++mi) {
      const int off = abase + 8192 + mi * 2048;
      a1[mi][0] = *(const bf16x8*)(Ac + off);
      a1[mi][1] = *(const bf16x8*)(Ac + (off ^ 64));
    }
    __builtin_amdgcn_s_setprio(1);
#pragma unroll
    for (int mi = 0; mi < 4; ++mi)
#pragma unroll
      for (int ni = 0; ni < 2; ++ni) {
        acc[mi + 4][ni + 2] = __builtin_amdgcn_mfma_f32_16x16x32_bf16(a1[mi][0], b23[ni][0], acc[mi + 4][ni + 2], 0, 0, 0);
        acc[mi + 4][ni + 2] = __builtin_amdgcn_mfma_f32_16x16x32_bf16(a1[mi][1], b23[ni][1], acc[mi + 4][ni + 2], 0, 0, 0);
      }
    __builtin_amdgcn_s_setprio(0);

    // barrier (a): all waves' cb-A reads complete -> cb-A may be overwritten
    asm volatile("s_waitcnt lgkmcnt(0)" ::: "memory");
    __builtin_amdgcn_s_barrier();

    if (ti + 2 < NT) { STAGE_A(cb, 0, ti + 2); STAGE_A(cb, 1, ti + 2); }

    __builtin_amdgcn_s_setprio(1);
#pragma unroll
    for (int mi = 0; mi < 4; ++mi)
#pragma unroll
      for (int ni = 0; ni < 2; ++ni) {
        acc[mi + 4][ni] = __builtin_amdgcn_mfma_f32_16x16x32_bf16(a1[mi][0], b01[ni][0], acc[mi + 4][ni], 0, 0, 0);
        acc[mi + 4][ni] = __builtin_amdgcn_mfma_f32_16x16x32_bf16(a1[mi][1], b01[ni][1], acc[mi + 4][ni], 0, 0, 0);
      }
    __builtin_amdgcn_s_setprio(0);

    // barrier (b): tile t+1 fully landed; A(t+2) (newest 4 loads) in flight
    if (ti + 2 < NT) {
      asm volatile("s_waitcnt vmcnt(4)" ::: "memory");
    } else {
      asm volatile("s_waitcnt vmcnt(0)" ::: "memory");
    }
    __builtin_amdgcn_s_barrier();
  }
#undef STAGE_A
#undef STAGE_B

  // ---- epilogue: C row = m0+wm*128+mi*16+qq*4+r, col = n0+wn*64+ni*16+lm
#pragma unroll
  for (int mi = 0; mi < 8; ++mi) {
    const int rbase = m0 + wm * 128 + mi * 16 + qq * 4;
    const int b = rbase / 3136;                 // batch (MODE 0); rbase%4==0
    const int mj = rbase - b * 3136;
#pragma unroll
    for (int ni = 0; ni < 4; ++ni) {
      const int col = n0 + wn * 64 + ni * 16 + lm;
      if (MODE == 0) {
        if (col < 768) {
          // Qb[m][768], relu+scale
#pragma unroll
          for (int r = 0; r < 4; ++r) {
            float v = fmaxf(acc[mi][ni][r], 0.0f) + 0.125f;
            ((u16*)out)[(size_t)(rbase + r) * 768 + col] = f2b(v);
          }
        } else {
          const bool isV = (col >= 1536);
          const int cc = col - (isV ? 1536 : 768);
          const int h = cc >> 6, e = cc & 63;
          ushort4 pk;
          float v0 = acc[mi][ni][0], v1 = acc[mi][ni][1];
          float v2 = acc[mi][ni][2], v3 = acc[mi][ni][3];
          if (!isV) {
            v0 = fmaxf(v0, 0.0f) + 0.125f; v1 = fmaxf(v1, 0.0f) + 0.125f;
            v2 = fmaxf(v2, 0.0f) + 0.125f; v3 = fmaxf(v3, 0.0f) + 0.125f;
          }
          pk.x = f2b(v0); pk.y = f2b(v1); pk.z = f2b(v2); pk.w = f2b(v3);
          u16* dst = (u16*)out + (isV ? 2 * QB_ELE : QB_ELE)
                   + ((size_t)((b * 12 + h) * 64 + e)) * 3136 + mj;
          *(ushort4*)dst = pk;
        }
      } else {
        const float bv = bias[col];
#pragma unroll
        for (int r = 0; r < 4; ++r) {
          float v = acc[mi][ni][r];
          const size_t idxo = (size_t)(rbase + r) * NN + col;
          if (MODE == 1) {
            ((float*)out)[idxo] = v + bv + res[idxo];
          } else if (MODE == 2) {
            ((u16*)out)[idxo] = f2b(v + bv);
          } else {
            ((float*)out)[idxo] = v + bv + res[idxo];
          }
        }
      }
    }
  }
}

// ---------------- ksum[bh][e] = sum_m KT[bh][e][m] (KT already relu'd) ------
__global__ __launch_bounds__(256) void ksum_kernel(const u16* __restrict__ KT,
    float* __restrict__ KS)
{
  const int bh = blockIdx.x;        // 0..95
  const int t = threadIdx.x;
  const int w = t >> 6, l = t & 63;
  const u16* base = KT + (size_t)(bh * 64 + w * 16) * 3136;
  for (int r = 0; r < 16; ++r) {
    float s = 0.f;
    const u16* row = base + (size_t)r * 3136;
#pragma unroll
    for (int p = 0; p < 7; ++p) {
      const int m = p * 512 + l * 8;
      if (m < 3136) {
        bf16x8 v = *(const bf16x8*)(row + m);
#pragma unroll
        for (int j = 0; j < 8; ++j) s += (float)v[j];
      }
    }
#pragma unroll
    for (int off = 32; off > 0; off >>= 1) s += __shfl_xor(s, off, 64);
    if (l == 0) KS[bh * 64 + w * 16 + r] = s;
  }
}

// ---------------- kv[bh] = KT[bh] @ VT[bh]^T via MFMA (R3) ------------------
// Per (bh, s): 64x64 x K=448 slice. No LDS, no barriers: A-frag = 16B read
// of a KT row, B-frag = 16B read of a VT row (both m-contiguous). fp32
// atomicAdd accumulation across the 7 m-splits.
__global__ __launch_bounds__(256) void kv_mfma(const u16* __restrict__ KT,
    const u16* __restrict__ VT, float* __restrict__ kv)
{
  const int bh = blockIdx.x;        // 0..95
  const int s = blockIdx.y;         // 0..6
  const int t = threadIdx.x;
  const int l = t & 63, w = t >> 6;
  const int lm = l & 15, qq = l >> 4;
  const size_t mj0 = (size_t)s * 448;
  const u16* ka = KT + (size_t)(bh * 64 + w * 16 + lm) * 3136 + mj0 + qq * 8;
  const u16* vb = VT + (size_t)(bh * 64 + lm) * 3136 + mj0 + qq * 8;

  f32x4 acc[4];
#pragma unroll
  for (int ni = 0; ni < 4; ++ni) acc[ni] = (f32x4){0.f, 0.f, 0.f, 0.f};

#pragma unroll 4
  for (int kk = 0; kk < 14; ++kk) {
    bf16x8 a = *(const bf16x8*)(ka + kk * 32);
#pragma unroll
    for (int ni = 0; ni < 4; ++ni) {
      bf16x8 b = *(const bf16x8*)(vb + (size_t)ni * 16 * 3136 + kk * 32);
      acc[ni] = __builtin_amdgcn_mfma_f32_16x16x32_bf16(a, b, acc[ni], 0, 0, 0);
    }
  }
  float* dst = kv + (size_t)bh * 4096;
#pragma unroll
  for (int ni = 0; ni < 4; ++ni)
#pragma unroll
    for (int r = 0; r < 4; ++r)
      atomicAdd(&dst[(w * 16 + qq * 4 + r) * 64 + ni * 16 + lm], acc[ni][r]);
}

// ---------------- out = (q_ @ kv) * z ----------------
__global__ __launch_bounds__(256) void attn_out(const u16* __restrict__ qb,
    const float* __restrict__ kv, const float* __restrict__ ksum,
    u16* __restrict__ outp)
{
  const int chunk = blockIdx.x;   // 0..48
  const int h = blockIdx.y;       // 0..11
  const int b = blockIdx.z;       // 0..7
  __shared__ float kvs[4096];
  __shared__ float kss[64];
  __shared__ float qs[4096];      // [wave][16 tok][64 e]
  const int t = threadIdx.x;
  const float* kvsrc = kv + (size_t)(b * 12 + h) * 4096;
  for (int i = t; i < 1024; i += 256)
    ((float4*)kvs)[i] = ((const float4*)kvsrc)[i];
  if (t < 64) kss[t] = ksum[(b * 12 + h) * 64 + t];
  __syncthreads();
  const int wv = t >> 6, lane = t & 63;
  float* qw = &qs[wv * 1024];
  const size_t tok0 = (size_t)b * MJ + chunk * 64 + wv * 16;
#pragma unroll
  for (int i = 0; i < 16; ++i) {
    float q = b2f(qb[(tok0 + i) * 768 + h * 64 + lane]);
    float pd = q * kss[lane];
#pragma unroll
    for (int off = 32; off > 0; off >>= 1) pd += __shfl_xor(pd, off, 64);
    qw[i * 64 + lane] = q * (1.0f / (pd + 1e-6f));
  }
  float o[16];
#pragma unroll
  for (int i = 0; i < 16; ++i) o[i] = 0.f;
  for (int e = 0; e < 64; ++e) {
    const float kvc = kvs[e * 64 + lane];
#pragma unroll
    for (int i = 0; i < 16; ++i) o[i] += qw[i * 64 + e] * kvc;
  }
#pragma unroll
  for (int i = 0; i < 16; ++i)
    outp[(tok0 + i) * 768 + h * 64 + lane] = f2b(o[i]);
}

// -------- depthwise 3x3 conv + exact GELU, in place (vectorized) --------
__global__ __launch_bounds__(256) void dwconv_gelu(u16* __restrict__ hdn,
    const float* __restrict__ w, const float* __restrict__ bias)
{
  __shared__ u16 pl[196 * 136];
  const int cb = blockIdx.x;     // 0..23
  const int fr = blockIdx.y;     // 0..127
  const int t = threadIdx.x;
  const int c0 = cb * 128;
  u16* base = hdn + (size_t)fr * 196 * HID + c0;
#pragma unroll
  for (int i = 0; i < 13; ++i) {
    int idx = i * 256 + t;
    if (idx < 3136) {
      int p = idx >> 4, cq = idx & 15;
      *(uint4*)&pl[p * 136 + cq * 8] = *(const uint4*)(base + (size_t)p * HID + cq * 8);
    }
  }
  __syncthreads();
  const int pc = t & 31;           // channel quad: c = c0 + pc*4
  const int pg = t >> 5;           // position group 0..7
  const int cc = pc * 4;
  float wr[36];
#pragma unroll
  for (int k = 0; k < 9; ++k)
#pragma unroll
    for (int u = 0; u < 4; ++u) wr[k * 4 + u] = w[(c0 + cc + u) * 9 + k];
  float bv[4];
#pragma unroll
  for (int u = 0; u < 4; ++u) bv[u] = bias[c0 + cc + u];

  for (int j = 0; j < 25; ++j) {
    const int p = pg + j * 8;
    if (p >= 196) break;
    const int py = p / 14, px = p % 14;
    float a0 = bv[0], a1 = bv[1], a2 = bv[2], a3 = bv[3];
#pragma unroll
    for (int ky = 0; ky < 3; ++ky) {
      int yy = py + ky - 1;
      if (yy < 0 || yy > 13) continue;
#pragma unroll
      for (int kx = 0; kx < 3; ++kx) {
        int xx = px + kx - 1;
        if (xx < 0 || xx > 13) continue;
        ushort4 tv = *(const ushort4*)&pl[(yy * 14 + xx) * 136 + cc];
        const float* wk = &wr[(ky * 3 + kx) * 4];
        a0 += wk[0] * b2f(tv.x);
        a1 += wk[1] * b2f(tv.y);
        a2 += wk[2] * b2f(tv.z);
        a3 += wk[3] * b2f(tv.w);
      }
    }
    ushort4 r;
    r.x = f2b(0.5f * a0 * (1.0f + erff(a0 * 0.70710678118654752f)));
    r.y = f2b(0.5f * a1 * (1.0f + erff(a1 * 0.70710678118654752f)));
    r.z = f2b(0.5f * a2 * (1.0f + erff(a2 * 0.70710678118654752f)));
    r.w = f2b(0.5f * a3 * (1.0f + erff(a3 * 0.70710678118654752f)));
    *(ushort4*)(base + (size_t)p * HID + cc) = r;
  }
}

// ---- dynamic-LDS attribute (128 KiB > 64 KiB default) + fallback buffer ----
static void set_gemm_attrs() {
  (void)hipFuncSetAttribute(reinterpret_cast<const void*>(&gemm8<0, 9, 2304, 768>),
                            hipFuncAttributeMaxDynamicSharedMemorySize, 131072);
  (void)hipFuncSetAttribute(reinterpret_cast<const void*>(&gemm8<1, 3, 768, 768>),
                            hipFuncAttributeMaxDynamicSharedMemorySize, 131072);
  (void)hipFuncSetAttribute(reinterpret_cast<const void*>(&gemm8<2, 12, 3072, 768>),
                            hipFuncAttributeMaxDynamicSharedMemorySize, 131072);
  (void)hipFuncSetAttribute(reinterpret_cast<const void*>(&gemm8<3, 3, 768, 3072>),
                            hipFuncAttributeMaxDynamicSharedMemorySize, 131072);
}
struct WsInit {
  WsInit() {
    (void)hipMalloc(&g_buf, WS_NEED);   // initializes runtime too
    set_gemm_attrs();
  }
};
static WsInit g_wsinit;

extern "C" void kernel_launch(void* const* d_in, const int* in_sizes, int n_in,
                              void* d_out, int out_size, void* d_ws, size_t ws_size,
                              hipStream_t stream)
{
  (void)in_sizes; (void)n_in; (void)out_size;
  static bool attrs_once = [] { set_gemm_attrs(); return true; }();
  (void)attrs_once;

  const float* x     = (const float*)d_in[0];
  const float* ln1w  = (const float*)d_in[1];
  const float* ln1b  = (const float*)d_in[2];
  const float* qkvw  = (const float*)d_in[3];
  const float* projw = (const float*)d_in[4];
  const float* projb = (const float*)d_in[5];
  const float* ln2w  = (const float*)d_in[6];
  const float* ln2b  = (const float*)d_in[7];
  const float* fc1w  = (const float*)d_in[8];
  const float* fc1b  = (const float*)d_in[9];
  const float* dww   = (const float*)d_in[10];
  const float* dwb   = (const float*)d_in[11];
  const float* fc2w  = (const float*)d_in[12];
  const float* fc2b  = (const float*)d_in[13];

  char* p = (ws_size >= WS_NEED) ? (char*)d_ws : (char*)g_buf;
  u16* WQKV  = (u16*)p;   p += (size_t)2304 * 768 * 2;
  u16* WPROJ = (u16*)p;   p += (size_t)768 * 768 * 2;
  u16* WFC1  = (u16*)p;   p += (size_t)3072 * 768 * 2;
  u16* WFC2  = (u16*)p;   p += (size_t)768 * 3072 * 2;
  u16* XN    = (u16*)p;   p += SZ_XN;    // xn1 / attn_out
  u16* QKV   = (u16*)p;   p += SZ_QKV;   // Qb | KT | VT ; later xn2 in Qb
  float* X2  = (float*)p; p += SZ_X2;    // residual after attn (fp32)
  u16* HDN   = (u16*)p;   p += SZ_HDN;   // fc1 out, conv in place
  float* KV  = (float*)p; p += SZ_KV;
  float* KS  = (float*)p; p += SZ_KS;

  u16* KT = QKV + QB_ELE;
  u16* VT = QKV + 2 * QB_ELE;

  cvt_f32_bf16<<<(2304*768/4 + 255)/256, 256, 0, stream>>>(qkvw, WQKV, 2304*768/4);
  cvt_f32_bf16<<<(768*768/4 + 255)/256, 256, 0, stream>>>(projw, WPROJ, 768*768/4);
  cvt_f32_bf16<<<(3072*768/4 + 255)/256, 256, 0, stream>>>(fc1w, WFC1, 3072*768/4);
  cvt_f32_bf16<<<(768*3072/4 + 255)/256, 256, 0, stream>>>(fc2w, WFC2, 768*3072/4);

  const int nz = 96 * 4096;              // KV accumulators
  zero_f32<<<(nz + 255) / 256, 256, 0, stream>>>(KV, nz);
  ln_kernel<<<NTOKENS / 4, 256, 0, stream>>>(x, ln1w, ln1b, XN);
  gemm8<0, 9, 2304, 768><<<98 * 9, 512, 131072, stream>>>(XN, WQKV, nullptr, nullptr, QKV);
  ksum_kernel<<<96, 256, 0, stream>>>(KT, KS);
  kv_mfma<<<dim3(96, 7), 256, 0, stream>>>(KT, VT, KV);
  attn_out<<<dim3(49, 12, 8), 256, 0, stream>>>(QKV, KV, KS, XN);
  gemm8<1, 3, 768, 768><<<98 * 3, 512, 131072, stream>>>(XN, WPROJ, projb, x, X2);
  ln_kernel<<<NTOKENS / 4, 256, 0, stream>>>(X2, ln2w, ln2b, QKV);
  gemm8<2, 12, 3072, 768><<<98 * 12, 512, 131072, stream>>>(QKV, WFC1, fc1b, nullptr, HDN);
  dwconv_gelu<<<dim3(24, 128), 256, 0, stream>>>(HDN, dww, dwb);
  gemm8<3, 3, 768, 3072><<<98 * 3, 512, 131072, stream>>>(HDN, WFC2, fc2b, X2, (float*)d_out);
}